// Round 1
// baseline (1417.928 us; speedup 1.0000x reference)
//
#include <hip/hip_runtime.h>

// ---------------------------------------------------------------------------
// GeoRegionSampler: restructured pipeline
//   X = [bilinear_fea | pts] (bf16, padded 1026->1056)
//   Wcomb = Wa1 @ Wd   (bf16 MFMA GEMM, N padded to 1152 w/ predicated store)
//   Z1 = X @ Wcomb^T ; Z2 = X[fi] @ Wa2^T ; czero = b_diff@Wa1^T + b_agg
//   h[b,s,k] = relu(Z1[idx]-Z1[fi]+Z2[s]+czero) -> LN -> mean_k  (fused)
//   final: fp32 split-K GEMMs (M=32, memory bound)
// FPS/kNN: fp32 bit-exact (fp contract off), first-index tie-break.
// ---------------------------------------------------------------------------

typedef float f32x4 __attribute__((ext_vector_type(4)));
typedef short bf16x8 __attribute__((ext_vector_type(8)));
typedef unsigned short u16;
typedef u16 u16x4 __attribute__((ext_vector_type(4)));
typedef unsigned int u32;
typedef u32 u32x4 __attribute__((ext_vector_type(4)));

typedef const void __attribute__((address_space(1)))* gvp;
typedef void __attribute__((address_space(3)))* svp;

__device__ __forceinline__ u16 f2bf(float f) {
  union { float f; u32 u; } x; x.f = f;
  u32 r = x.u + 0x7fffu + ((x.u >> 16) & 1u);
  return (u16)(r >> 16);
}

#define KP 1056   // padded Dp (1026 -> 33*32)
#define NP0 1152  // padded N for weight-combine GEMM (9*128)

// ---------------- fmap transpose: (B,C,H,W) -> (B,HW,C) --------------------
__global__ __launch_bounds__(256) void fmap_transpose_kernel(const float* __restrict__ fmap,
                                                             float* __restrict__ fmapT) {
  __shared__ float tbuf[32][33];
  int tx = threadIdx.x & 31, ty = threadIdx.x >> 5;
  int hwt = blockIdx.x * 32, ct = blockIdx.y * 32, b = blockIdx.z;
  const float* src = fmap + (size_t)b * 1024 * 576;
  #pragma unroll
  for (int j = 0; j < 4; ++j) {
    int c = ct + ty + 8 * j;
    tbuf[ty + 8 * j][tx] = src[(size_t)c * 576 + hwt + tx];
  }
  __syncthreads();
  float* dst = fmapT + (size_t)b * 576 * 1024;
  #pragma unroll
  for (int j = 0; j < 4; ++j) {
    int hw = hwt + ty + 8 * j;
    dst[(size_t)hw * 1024 + ct + tx] = tbuf[tx][ty + 8 * j];
  }
}

// ---------------- bilinear -> X bf16 rows [fea(1024) | pts(2) | 0 pad] -----
__global__ __launch_bounds__(256) void bilinear_kernel(const float* __restrict__ fmapT,
                                                       const float* __restrict__ pts,
                                                       u16* __restrict__ X) {
  int blk = blockIdx.x;              // b*512 + n
  int t = threadIdx.x;
  float p0 = pts[(size_t)blk * 2], p1 = pts[(size_t)blk * 2 + 1];
  float gy = p0 * 23.f, gx = p1 * 23.f;
  float y0f = floorf(gy), x0f = floorf(gx);
  float wy = gy - y0f, wx = gx - x0f;
  int y0 = (int)y0f; y0 = y0 < 0 ? 0 : (y0 > 23 ? 23 : y0);
  int x0 = (int)x0f; x0 = x0 < 0 ? 0 : (x0 > 23 ? 23 : x0);
  int y1 = y0 + 1 > 23 ? 23 : y0 + 1;
  int x1 = x0 + 1 > 23 ? 23 : x0 + 1;
  int b = blk >> 9;
  const f32x4* r00 = (const f32x4*)(fmapT + ((size_t)b * 576 + y0 * 24 + x0) * 1024);
  const f32x4* r01 = (const f32x4*)(fmapT + ((size_t)b * 576 + y0 * 24 + x1) * 1024);
  const f32x4* r10 = (const f32x4*)(fmapT + ((size_t)b * 576 + y1 * 24 + x0) * 1024);
  const f32x4* r11 = (const f32x4*)(fmapT + ((size_t)b * 576 + y1 * 24 + x1) * 1024);
  float w00 = (1.f - wy) * (1.f - wx), w01 = (1.f - wy) * wx;
  float w10 = wy * (1.f - wx), w11 = wy * wx;
  f32x4 v = r00[t] * w00 + r01[t] * w01 + r10[t] * w10 + r11[t] * w11;
  u16x4 o;
  #pragma unroll
  for (int c = 0; c < 4; ++c) o[c] = f2bf(v[c]);
  size_t ro = (size_t)blk * KP;
  *(u16x4*)(X + ro + t * 4) = o;
  if (t == 0) { X[ro + 1024] = f2bf(p0); X[ro + 1025] = f2bf(p1); }
  if (t < 15) ((u32*)(X + ro + 1026))[t] = 0;
}

// ---------------- FPS: one wave per batch, bit-exact ------------------------
template <int PPL>
__global__ void fps_kernel(const float* __restrict__ pts, int* __restrict__ fi,
                           int Np, int S) {
  #pragma clang fp contract(off)
  int b = blockIdx.x;
  int lane = threadIdx.x;
  float px[PPL], py[PPL], dist[PPL];
  #pragma unroll
  for (int j = 0; j < PPL; ++j) {
    int n = j * 64 + lane;
    px[j] = pts[((size_t)b * Np + n) * 2];
    py[j] = pts[((size_t)b * Np + n) * 2 + 1];
    dist[j] = 1e10f;
  }
  int far = 0;
  for (int s = 0; s < S; ++s) {
    if (lane == 0) fi[b * S + s] = far;
    float cx = pts[((size_t)b * Np + far) * 2];
    float cy = pts[((size_t)b * Np + far) * 2 + 1];
    float bv = -1.f; int bi = 0;
    #pragma unroll
    for (int j = 0; j < PPL; ++j) {
      float dx = px[j] - cx, dy = py[j] - cy;
      float d = dx * dx + dy * dy;
      float nd = fminf(dist[j], d);
      dist[j] = nd;
      if (nd > bv) { bv = nd; bi = j * 64 + lane; }
    }
    #pragma unroll
    for (int off = 32; off; off >>= 1) {
      float ov = __shfl_xor(bv, off);
      int oi = __shfl_xor(bi, off);
      if (ov > bv || (ov == bv && oi < bi)) { bv = ov; bi = oi; }
    }
    far = bi;
  }
}

// ---------------- kNN: one wave per (b,s), bit-exact ------------------------
template <int PPL>
__global__ __launch_bounds__(256) void knn_kernel(const float* __restrict__ qpts,
                                                  const float* __restrict__ rpts,
                                                  int* __restrict__ idxK, int Np, int S) {
  #pragma clang fp contract(off)
  int lane = threadIdx.x & 63, wv = threadIdx.x >> 6;
  int q = blockIdx.x * 4 + wv;
  int b = q / S;
  float ax = qpts[(size_t)q * 2], ay = qpts[(size_t)q * 2 + 1];
  float a2 = ax * ax + ay * ay;
  float d2[PPL];
  #pragma unroll
  for (int j = 0; j < PPL; ++j) {
    int n = j * 64 + lane;
    float bx = rpts[((size_t)b * Np + n) * 2];
    float by = rpts[((size_t)b * Np + n) * 2 + 1];
    float b2 = bx * bx + by * by;
    float dot = ax * bx + ay * by;
    float t = a2 + b2;
    float m2 = 2.f * dot;
    d2[j] = t - m2;
  }
  for (int k = 0; k < 24; ++k) {
    float bv = 3.4e38f; int bi = 1 << 30;
    #pragma unroll
    for (int j = 0; j < PPL; ++j)
      if (d2[j] < bv) { bv = d2[j]; bi = j * 64 + lane; }
    #pragma unroll
    for (int off = 32; off; off >>= 1) {
      float ov = __shfl_xor(bv, off);
      int oi = __shfl_xor(bi, off);
      if (ov < bv || (ov == bv && oi < bi)) { bv = ov; bi = oi; }
    }
    if (lane == 0) idxK[(size_t)q * 24 + k] = bi;
    #pragma unroll
    for (int j = 0; j < PPL; ++j)
      if (j * 64 + lane == bi) d2[j] = 3.4e38f;
  }
}

// ---------------- gather X rows at fi; emit new_pts -------------------------
__global__ __launch_bounds__(128) void gather_fi_kernel(const u16* __restrict__ Xsrc,
                                                        const float* __restrict__ pts,
                                                        const int* __restrict__ fi,
                                                        u16* __restrict__ Xg,
                                                        float* __restrict__ npts,
                                                        int Np, int S) {
  int q = blockIdx.x;
  int b = q / S;
  int t = threadIdx.x;
  int r = fi[q];
  const u32x4* src = (const u32x4*)(Xsrc + ((size_t)b * Np + r) * KP);
  u32x4* dst = (u32x4*)(Xg + (size_t)q * KP);
  dst[t] = src[t];
  int t2 = t + 128;
  if (t2 < 132) dst[t2] = src[t2];
  if (t == 0) {
    npts[(size_t)q * 2] = pts[((size_t)b * Np + r) * 2];
    npts[(size_t)q * 2 + 1] = pts[((size_t)b * Np + r) * 2 + 1];
  }
}

// ---------------- weight prep ----------------------------------------------
__global__ __launch_bounds__(256) void wd_transpose_kernel(const float* __restrict__ Wd,
                                                           u16* __restrict__ WdT) {
  __shared__ float tbuf[32][33];
  int tx = threadIdx.x & 31, ty = threadIdx.x >> 5;
  int ot = blockIdx.x * 32, dt = blockIdx.y * 32;
  #pragma unroll
  for (int j = 0; j < 4; ++j) {
    int o = ot + ty + 8 * j, d = dt + tx;
    tbuf[ty + 8 * j][tx] = (o < 1026 && d < 1026) ? Wd[(size_t)o * 1026 + d] : 0.f;
  }
  __syncthreads();
  #pragma unroll
  for (int j = 0; j < 4; ++j) {
    int d = dt + ty + 8 * j, o = ot + tx;
    if (o < KP) WdT[(size_t)d * KP + o] = f2bf(tbuf[tx][ty + 8 * j]);
  }
}

__global__ __launch_bounds__(256) void wagg_convert_kernel(const float* __restrict__ Wagg,
                                                           u16* __restrict__ Wa1,
                                                           u16* __restrict__ Wa2) {
  int c = blockIdx.x, t = threadIdx.x;
  const float* row = Wagg + (size_t)c * 2052;
  for (int d = t; d < KP; d += 256) {
    Wa1[(size_t)c * KP + d] = (d < 1026) ? f2bf(row[d]) : (u16)0;
    Wa2[(size_t)c * KP + d] = (d < 1026) ? f2bf(row[1026 + d]) : (u16)0;
  }
}

__global__ __launch_bounds__(256) void czero_kernel(const float* __restrict__ bdiff,
                                                    const float* __restrict__ Wagg,
                                                    const float* __restrict__ bagg,
                                                    float* __restrict__ czero) {
  int lane = threadIdx.x & 63, wv = threadIdx.x >> 6;
  int c = blockIdx.x * 4 + wv;
  float acc = 0.f;
  for (int o = lane; o < 1026; o += 64) acc += bdiff[o] * Wagg[(size_t)c * 2052 + o];
  #pragma unroll
  for (int off = 32; off; off >>= 1) acc += __shfl_xor(acc, off);
  if (lane == 0) czero[c] = acc + bagg[c];
}

// ---------------- bf16 MFMA GEMM: C[M,N] = A[M,K] @ Bt[N,K]^T ---------------
template <int BF16OUT>
__global__ __launch_bounds__(256) void gemm_bt_kernel(const u16* __restrict__ A,
                                                      const u16* __restrict__ Bt,
                                                      void* __restrict__ Cout,
                                                      int M, int N, int K, int ldc, int nvalid) {
  __shared__ __align__(16) u16 As[128 * 32];
  __shared__ __align__(16) u16 Bs[128 * 32];
  const int tid = threadIdx.x;
  const int lane = tid & 63;
  const int wv = tid >> 6;
  const int m0 = blockIdx.y * 128;
  const int n0 = blockIdx.x * 128;
  const int wm = (wv >> 1) * 64;
  const int wn = (wv & 1) * 64;

  f32x4 acc[4][4];
  #pragma unroll
  for (int i = 0; i < 4; ++i)
    #pragma unroll
    for (int j = 0; j < 4; ++j)
      #pragma unroll
      for (int c = 0; c < 4; ++c) acc[i][j][c] = 0.f;

  const int ch0 = wv * 2;
  const int rin = lane >> 2;        // row within 16-row chunk
  const int cin = (lane & 3) * 8;   // u16 col offset

  for (int k0 = 0; k0 < K; k0 += 32) {
    #pragma unroll
    for (int i = 0; i < 2; ++i) {
      const int ch = ch0 + i;
      const int row = ch * 16 + rin;
      const u16* ga = A + (size_t)(m0 + row) * K + (k0 + cin);
      const u16* gb = Bt + (size_t)(n0 + row) * K + (k0 + cin);
      __builtin_amdgcn_global_load_lds((gvp)ga, (svp)(As + ch * 512), 16, 0, 0);
      __builtin_amdgcn_global_load_lds((gvp)gb, (svp)(Bs + ch * 512), 16, 0, 0);
    }
    __syncthreads();
    const int rf = lane & 15;
    const int qf = (lane >> 4) * 8;
    bf16x8 af[4], bfv[4];
    #pragma unroll
    for (int mi = 0; mi < 4; ++mi)
      af[mi] = *(const bf16x8*)(As + (wm + mi * 16 + rf) * 32 + qf);
    #pragma unroll
    for (int ni = 0; ni < 4; ++ni)
      bfv[ni] = *(const bf16x8*)(Bs + (wn + ni * 16 + rf) * 32 + qf);
    #pragma unroll
    for (int mi = 0; mi < 4; ++mi)
      #pragma unroll
      for (int ni = 0; ni < 4; ++ni)
        acc[mi][ni] = __builtin_amdgcn_mfma_f32_16x16x32_bf16(af[mi], bfv[ni], acc[mi][ni], 0, 0, 0);
    __syncthreads();
  }

  const int rq = (lane >> 4) * 4;
  const int cf = lane & 15;
  #pragma unroll
  for (int mi = 0; mi < 4; ++mi) {
    #pragma unroll
    for (int ni = 0; ni < 4; ++ni) {
      const int col = n0 + wn + ni * 16 + cf;
      #pragma unroll
      for (int r = 0; r < 4; ++r) {
        const int row = m0 + wm + mi * 16 + rq + r;
        const float v = acc[mi][ni][r];
        if (BF16OUT) {
          if (col < nvalid) ((u16*)Cout)[(size_t)row * ldc + col] = f2bf(v);
        } else {
          ((float*)Cout)[(size_t)row * ldc + col] = v;
        }
      }
    }
  }
}

// ---------------- fused gather + relu + LN + mean_k -------------------------
template <int BF16OUT>
__global__ __launch_bounds__(256) void h_epilogue_kernel(const float* __restrict__ Z1,
                                                         const float* __restrict__ Z2g,
                                                         const float* __restrict__ czero,
                                                         const int* __restrict__ idxK,
                                                         const int* __restrict__ fi,
                                                         const float* __restrict__ g,
                                                         const float* __restrict__ bb,
                                                         const float* __restrict__ npts,
                                                         void* __restrict__ outp,
                                                         int Np, int S) {
  __shared__ float r1[4];
  __shared__ float r2[4];
  int q = blockIdx.x;
  int b = q / S;
  int t = threadIdx.x;
  int lane = t & 63, wv = t >> 6;
  int fiv = fi[q];
  const f32x4* z2 = (const f32x4*)(Z2g + (size_t)q * 1024);
  const f32x4* zf = (const f32x4*)(Z1 + ((size_t)b * Np + fiv) * 1024);
  const f32x4* cz = (const f32x4*)czero;
  f32x4 base = z2[t] + cz[t] - zf[t];
  f32x4 gv = ((const f32x4*)g)[t];
  f32x4 bv = ((const f32x4*)bb)[t];
  f32x4 acc;
  #pragma unroll
  for (int c = 0; c < 4; ++c) acc[c] = 0.f;
  for (int k = 0; k < 24; ++k) {
    int n = idxK[(size_t)q * 24 + k];
    const f32x4* zr = (const f32x4*)(Z1 + ((size_t)b * Np + n) * 1024);
    f32x4 v = zr[t] + base;
    #pragma unroll
    for (int c = 0; c < 4; ++c) v[c] = fmaxf(v[c], 0.f);
    float s1 = v[0] + v[1] + v[2] + v[3];
    float s2 = v[0] * v[0] + v[1] * v[1] + v[2] * v[2] + v[3] * v[3];
    #pragma unroll
    for (int off = 32; off; off >>= 1) {
      s1 += __shfl_xor(s1, off);
      s2 += __shfl_xor(s2, off);
    }
    if (lane == 0) { r1[wv] = s1; r2[wv] = s2; }
    __syncthreads();
    s1 = r1[0] + r1[1] + r1[2] + r1[3];
    s2 = r2[0] + r2[1] + r2[2] + r2[3];
    __syncthreads();
    float m = s1 * (1.f / 1024.f);
    float var = s2 * (1.f / 1024.f) - m * m;
    float rs = rsqrtf(var + 1e-5f);
    #pragma unroll
    for (int c = 0; c < 4; ++c) acc[c] += (v[c] - m) * rs * gv[c] + bv[c];
  }
  #pragma unroll
  for (int c = 0; c < 4; ++c) acc[c] *= (1.f / 24.f);
  if (BF16OUT) {
    u16* X = (u16*)outp;
    size_t ro = (size_t)q * KP;
    u16x4 o4;
    #pragma unroll
    for (int c = 0; c < 4; ++c) o4[c] = f2bf(acc[c]);
    *(u16x4*)(X + ro + t * 4) = o4;
    if (t == 0) {
      X[ro + 1024] = f2bf(npts[(size_t)q * 2]);
      X[ro + 1025] = f2bf(npts[(size_t)q * 2 + 1]);
    }
    if (t < 15) ((u32*)(X + ro + 1026))[t] = 0;
  } else {
    ((f32x4*)outp)[(size_t)q * 256 + t] = acc;
  }
}

// ---------------- final fp32 GEMMs (M=32, memory-bound) ---------------------
__global__ __launch_bounds__(256) void x1_init_kernel(const float* __restrict__ bflat,
                                                      float* __restrict__ x1) {
  int i = blockIdx.x * 256 + threadIdx.x;  // 32768
  x1[i] = bflat[i & 1023];
}

__global__ __launch_bounds__(256) void flat_gemm_kernel(const float* __restrict__ fea2,
                                                        const float* __restrict__ Wf,
                                                        float* __restrict__ x1) {
  int t = threadIdx.x, bx = blockIdx.x;  // 512 blocks
  int ks = bx >> 7;                      // 0..3 (K split of 8192)
  int og = bx & 127;
  int f = og * 256 + t;                  // 0..32767
  int o = f >> 5, b = f & 31;
  const f32x4* wa = (const f32x4*)(Wf + (size_t)o * 32768 + ks * 8192);
  const f32x4* xa = (const f32x4*)(fea2 + (size_t)b * 32768 + ks * 8192);
  float acc = 0.f;
  #pragma unroll 8
  for (int i = 0; i < 2048; ++i) {
    f32x4 w = wa[i], x = xa[i];
    acc += w[0] * x[0] + w[1] * x[1] + w[2] * x[2] + w[3] * x[3];
  }
  atomicAdd(&x1[b * 1024 + o], acc);
}

__global__ __launch_bounds__(256) void dim_gemm_kernel(const float* __restrict__ x1,
                                                       const float* __restrict__ Wd,
                                                       const float* __restrict__ bdim,
                                                       float* __restrict__ out) {
  int f = blockIdx.x * 256 + threadIdx.x;  // 131072
  int o = f >> 5, b = f & 31;
  const f32x4* wa = (const f32x4*)(Wd + (size_t)o * 1024);
  const f32x4* xa = (const f32x4*)(x1 + (size_t)b * 1024);
  float acc = 0.f;
  #pragma unroll 8
  for (int i = 0; i < 256; ++i) {
    f32x4 w = wa[i], x = xa[i];
    acc += w[0] * x[0] + w[1] * x[1] + w[2] * x[2] + w[3] * x[3];
  }
  out[(size_t)b * 4096 + o] = acc + bdim[o];
}

// ---------------------------------------------------------------------------
extern "C" void kernel_launch(void* const* d_in, const int* in_sizes, int n_in,
                              void* d_out, int out_size, void* d_ws, size_t ws_size,
                              hipStream_t stream) {
  const float* fmap  = (const float*)d_in[0];
  const float* pts   = (const float*)d_in[1];
  const float* Wdiff = (const float*)d_in[2];
  const float* bdiff = (const float*)d_in[3];
  const float* Wagg  = (const float*)d_in[4];
  const float* bagg  = (const float*)d_in[5];
  const float* lng   = (const float*)d_in[6];
  const float* lnb   = (const float*)d_in[7];
  const float* Wflat = (const float*)d_in[8];
  const float* bflat = (const float*)d_in[9];
  const float* Wdim  = (const float*)d_in[10];
  const float* bdim  = (const float*)d_in[11];
  float* out = (float*)d_out;

  char* w = (char*)d_ws;
  size_t off = 0;
  auto alloc = [&](size_t n) { char* p = w + off; off += (n + 255) & ~(size_t)255; return p; };

  float* Z1    = (float*)alloc(16384ull * 1024 * 4);  // 67.1 MB (stage0/1 reuse)
  float* Z2g   = (float*)alloc(4096ull * 1024 * 4);   // 16.8 MB
  float* fmapT = Z1;  // alias: fmapT (75.5 MB) dead before any Z write
  u16* Xbf0  = (u16*)alloc(16384ull * KP * 2);
  u16* X1bf  = (u16*)alloc(4096ull * KP * 2);
  u16* Xg    = (u16*)alloc(4096ull * KP * 2);
  u16* WdT   = (u16*)alloc((size_t)NP0 * KP * 2);
  u16* Wa1   = (u16*)alloc(1024ull * KP * 2);
  u16* Wa2   = (u16*)alloc(1024ull * KP * 2);
  u16* Wcomb = (u16*)alloc(1024ull * KP * 2);
  float* czero = (float*)alloc(1024 * 4);
  int* fi0   = (int*)alloc(32 * 128 * 4);
  int* fi1   = (int*)alloc(32 * 32 * 4);
  int* idx0  = (int*)alloc(32 * 128 * 24 * 4);
  int* idx1  = (int*)alloc(32 * 32 * 24 * 4);
  float* npts0 = (float*)alloc(32 * 128 * 2 * 4);
  float* npts1 = (float*)alloc(32 * 32 * 2 * 4);
  float* fea2  = (float*)alloc(32ull * 32 * 1024 * 4);
  float* x1    = (float*)alloc(32 * 1024 * 4);

  // ---- stage-0 inputs
  fmap_transpose_kernel<<<dim3(18, 32, 32), 256, 0, stream>>>(fmap, fmapT);
  bilinear_kernel<<<16384, 256, 0, stream>>>(fmapT, pts, Xbf0);

  // ---- stage 0 (Np=512, S=128)
  fps_kernel<8><<<32, 64, 0, stream>>>(pts, fi0, 512, 128);
  gather_fi_kernel<<<4096, 128, 0, stream>>>(Xbf0, pts, fi0, Xg, npts0, 512, 128);
  knn_kernel<8><<<1024, 256, 0, stream>>>(npts0, pts, idx0, 512, 128);
  wd_transpose_kernel<<<dim3(33, 36), 256, 0, stream>>>(Wdiff, WdT);
  wagg_convert_kernel<<<1024, 256, 0, stream>>>(Wagg, Wa1, Wa2);
  czero_kernel<<<256, 256, 0, stream>>>(bdiff, Wagg, bagg, czero);
  gemm_bt_kernel<1><<<dim3(9, 8), 256, 0, stream>>>(Wa1, WdT, Wcomb, 1024, NP0, KP, KP, KP);
  gemm_bt_kernel<0><<<dim3(8, 128), 256, 0, stream>>>(Xbf0, Wcomb, Z1, 16384, 1024, KP, 1024, 1024);
  gemm_bt_kernel<0><<<dim3(8, 32), 256, 0, stream>>>(Xg, Wa2, Z2g, 4096, 1024, KP, 1024, 1024);
  h_epilogue_kernel<1><<<4096, 256, 0, stream>>>(Z1, Z2g, czero, idx0, fi0, lng, lnb, npts0,
                                                 X1bf, 512, 128);

  // ---- stage 1 (Np=128, S=32)
  fps_kernel<2><<<32, 64, 0, stream>>>(npts0, fi1, 128, 32);
  gather_fi_kernel<<<1024, 128, 0, stream>>>(X1bf, npts0, fi1, Xg, npts1, 128, 32);
  knn_kernel<2><<<256, 256, 0, stream>>>(npts1, npts0, idx1, 128, 32);
  wd_transpose_kernel<<<dim3(33, 36), 256, 0, stream>>>(Wdiff + 1026 * 1026, WdT);
  wagg_convert_kernel<<<1024, 256, 0, stream>>>(Wagg + 1024 * 2052, Wa1, Wa2);
  czero_kernel<<<256, 256, 0, stream>>>(bdiff + 1026, Wagg + 1024 * 2052, bagg + 1024, czero);
  gemm_bt_kernel<1><<<dim3(9, 8), 256, 0, stream>>>(Wa1, WdT, Wcomb, 1024, NP0, KP, KP, KP);
  gemm_bt_kernel<0><<<dim3(8, 32), 256, 0, stream>>>(X1bf, Wcomb, Z1, 4096, 1024, KP, 1024, 1024);
  gemm_bt_kernel<0><<<dim3(8, 8), 256, 0, stream>>>(Xg, Wa2, Z2g, 1024, 1024, KP, 1024, 1024);
  h_epilogue_kernel<0><<<1024, 256, 0, stream>>>(Z1, Z2g, czero, idx1, fi1, lng + 1024, lnb + 1024,
                                                 npts1, fea2, 128, 32);

  // ---- final MLP
  x1_init_kernel<<<128, 256, 0, stream>>>(bflat, x1);
  flat_gemm_kernel<<<512, 256, 0, stream>>>(fea2, Wflat, x1);
  dim_gemm_kernel<<<512, 256, 0, stream>>>(x1, Wdim, bdim, out);
}

// Round 2
// 1111.335 us; speedup vs baseline: 1.2759x; 1.2759x over previous
//
#include <hip/hip_runtime.h>

// ---------------------------------------------------------------------------
// GeoRegionSampler: restructured pipeline
//   X = [bilinear_fea | pts] (bf16, padded 1026->1056)
//   Wcomb = Wa1 @ Wd   (bf16 MFMA GEMM, N padded to 1152 w/ predicated store)
//   Z1 = X @ Wcomb^T ; Z2 = X[fi] @ Wa2^T ; czero = b_diff@Wa1^T + b_agg
//   h[b,s,k] = relu(Z1[idx]-Z1[fi]+Z2[s]+czero) -> LN -> mean_k  (fused)
//   final: fp32 register-tiled GEMMs (wave owns 4 weight rows, lanes
//   partition K, coalesced float4 weight streams; R1 fix of 578us kernel)
// FPS/kNN: fp32 bit-exact (fp contract off), first-index tie-break.
// ---------------------------------------------------------------------------

typedef float f32x4 __attribute__((ext_vector_type(4)));
typedef short bf16x8 __attribute__((ext_vector_type(8)));
typedef unsigned short u16;
typedef u16 u16x4 __attribute__((ext_vector_type(4)));
typedef unsigned int u32;
typedef u32 u32x4 __attribute__((ext_vector_type(4)));

typedef const void __attribute__((address_space(1)))* gvp;
typedef void __attribute__((address_space(3)))* svp;

__device__ __forceinline__ u16 f2bf(float f) {
  union { float f; u32 u; } x; x.f = f;
  u32 r = x.u + 0x7fffu + ((x.u >> 16) & 1u);
  return (u16)(r >> 16);
}

__device__ __forceinline__ float wave_sum64(float v) {
  #pragma unroll
  for (int off = 32; off; off >>= 1) v += __shfl_xor(v, off);
  return v;
}

#define KP 1056   // padded Dp (1026 -> 33*32)
#define NP0 1152  // padded N for weight-combine GEMM (9*128)

// ---------------- fmap transpose: (B,C,H,W) -> (B,HW,C) --------------------
__global__ __launch_bounds__(256) void fmap_transpose_kernel(const float* __restrict__ fmap,
                                                             float* __restrict__ fmapT) {
  __shared__ float tbuf[32][33];
  int tx = threadIdx.x & 31, ty = threadIdx.x >> 5;
  int hwt = blockIdx.x * 32, ct = blockIdx.y * 32, b = blockIdx.z;
  const float* src = fmap + (size_t)b * 1024 * 576;
  #pragma unroll
  for (int j = 0; j < 4; ++j) {
    int c = ct + ty + 8 * j;
    tbuf[ty + 8 * j][tx] = src[(size_t)c * 576 + hwt + tx];
  }
  __syncthreads();
  float* dst = fmapT + (size_t)b * 576 * 1024;
  #pragma unroll
  for (int j = 0; j < 4; ++j) {
    int hw = hwt + ty + 8 * j;
    dst[(size_t)hw * 1024 + ct + tx] = tbuf[tx][ty + 8 * j];
  }
}

// ---------------- bilinear -> X bf16 rows [fea(1024) | pts(2) | 0 pad] -----
__global__ __launch_bounds__(256) void bilinear_kernel(const float* __restrict__ fmapT,
                                                       const float* __restrict__ pts,
                                                       u16* __restrict__ X) {
  int blk = blockIdx.x;              // b*512 + n
  int t = threadIdx.x;
  float p0 = pts[(size_t)blk * 2], p1 = pts[(size_t)blk * 2 + 1];
  float gy = p0 * 23.f, gx = p1 * 23.f;
  float y0f = floorf(gy), x0f = floorf(gx);
  float wy = gy - y0f, wx = gx - x0f;
  int y0 = (int)y0f; y0 = y0 < 0 ? 0 : (y0 > 23 ? 23 : y0);
  int x0 = (int)x0f; x0 = x0 < 0 ? 0 : (x0 > 23 ? 23 : x0);
  int y1 = y0 + 1 > 23 ? 23 : y0 + 1;
  int x1 = x0 + 1 > 23 ? 23 : x0 + 1;
  int b = blk >> 9;
  const f32x4* r00 = (const f32x4*)(fmapT + ((size_t)b * 576 + y0 * 24 + x0) * 1024);
  const f32x4* r01 = (const f32x4*)(fmapT + ((size_t)b * 576 + y0 * 24 + x1) * 1024);
  const f32x4* r10 = (const f32x4*)(fmapT + ((size_t)b * 576 + y1 * 24 + x0) * 1024);
  const f32x4* r11 = (const f32x4*)(fmapT + ((size_t)b * 576 + y1 * 24 + x1) * 1024);
  float w00 = (1.f - wy) * (1.f - wx), w01 = (1.f - wy) * wx;
  float w10 = wy * (1.f - wx), w11 = wy * wx;
  f32x4 v = r00[t] * w00 + r01[t] * w01 + r10[t] * w10 + r11[t] * w11;
  u16x4 o;
  #pragma unroll
  for (int c = 0; c < 4; ++c) o[c] = f2bf(v[c]);
  size_t ro = (size_t)blk * KP;
  *(u16x4*)(X + ro + t * 4) = o;
  if (t == 0) { X[ro + 1024] = f2bf(p0); X[ro + 1025] = f2bf(p1); }
  if (t < 15) ((u32*)(X + ro + 1026))[t] = 0;
}

// ---------------- FPS: one wave per batch, bit-exact ------------------------
template <int PPL>
__global__ void fps_kernel(const float* __restrict__ pts, int* __restrict__ fi,
                           int Np, int S) {
  #pragma clang fp contract(off)
  int b = blockIdx.x;
  int lane = threadIdx.x;
  float px[PPL], py[PPL], dist[PPL];
  #pragma unroll
  for (int j = 0; j < PPL; ++j) {
    int n = j * 64 + lane;
    px[j] = pts[((size_t)b * Np + n) * 2];
    py[j] = pts[((size_t)b * Np + n) * 2 + 1];
    dist[j] = 1e10f;
  }
  int far = 0;
  for (int s = 0; s < S; ++s) {
    if (lane == 0) fi[b * S + s] = far;
    float cx = pts[((size_t)b * Np + far) * 2];
    float cy = pts[((size_t)b * Np + far) * 2 + 1];
    float bv = -1.f; int bi = 0;
    #pragma unroll
    for (int j = 0; j < PPL; ++j) {
      float dx = px[j] - cx, dy = py[j] - cy;
      float d = dx * dx + dy * dy;
      float nd = fminf(dist[j], d);
      dist[j] = nd;
      if (nd > bv) { bv = nd; bi = j * 64 + lane; }
    }
    #pragma unroll
    for (int off = 32; off; off >>= 1) {
      float ov = __shfl_xor(bv, off);
      int oi = __shfl_xor(bi, off);
      if (ov > bv || (ov == bv && oi < bi)) { bv = ov; bi = oi; }
    }
    far = bi;
  }
}

// ---------------- kNN: one wave per (b,s), bit-exact ------------------------
template <int PPL>
__global__ __launch_bounds__(256) void knn_kernel(const float* __restrict__ qpts,
                                                  const float* __restrict__ rpts,
                                                  int* __restrict__ idxK, int Np, int S) {
  #pragma clang fp contract(off)
  int lane = threadIdx.x & 63, wv = threadIdx.x >> 6;
  int q = blockIdx.x * 4 + wv;
  int b = q / S;
  float ax = qpts[(size_t)q * 2], ay = qpts[(size_t)q * 2 + 1];
  float a2 = ax * ax + ay * ay;
  float d2[PPL];
  #pragma unroll
  for (int j = 0; j < PPL; ++j) {
    int n = j * 64 + lane;
    float bx = rpts[((size_t)b * Np + n) * 2];
    float by = rpts[((size_t)b * Np + n) * 2 + 1];
    float b2 = bx * bx + by * by;
    float dot = ax * bx + ay * by;
    float t = a2 + b2;
    float m2 = 2.f * dot;
    d2[j] = t - m2;
  }
  for (int k = 0; k < 24; ++k) {
    float bv = 3.4e38f; int bi = 1 << 30;
    #pragma unroll
    for (int j = 0; j < PPL; ++j)
      if (d2[j] < bv) { bv = d2[j]; bi = j * 64 + lane; }
    #pragma unroll
    for (int off = 32; off; off >>= 1) {
      float ov = __shfl_xor(bv, off);
      int oi = __shfl_xor(bi, off);
      if (ov < bv || (ov == bv && oi < bi)) { bv = ov; bi = oi; }
    }
    if (lane == 0) idxK[(size_t)q * 24 + k] = bi;
    #pragma unroll
    for (int j = 0; j < PPL; ++j)
      if (j * 64 + lane == bi) d2[j] = 3.4e38f;
  }
}

// ---------------- gather X rows at fi; emit new_pts -------------------------
__global__ __launch_bounds__(128) void gather_fi_kernel(const u16* __restrict__ Xsrc,
                                                        const float* __restrict__ pts,
                                                        const int* __restrict__ fi,
                                                        u16* __restrict__ Xg,
                                                        float* __restrict__ npts,
                                                        int Np, int S) {
  int q = blockIdx.x;
  int b = q / S;
  int t = threadIdx.x;
  int r = fi[q];
  const u32x4* src = (const u32x4*)(Xsrc + ((size_t)b * Np + r) * KP);
  u32x4* dst = (u32x4*)(Xg + (size_t)q * KP);
  dst[t] = src[t];
  int t2 = t + 128;
  if (t2 < 132) dst[t2] = src[t2];
  if (t == 0) {
    npts[(size_t)q * 2] = pts[((size_t)b * Np + r) * 2];
    npts[(size_t)q * 2 + 1] = pts[((size_t)b * Np + r) * 2 + 1];
  }
}

// ---------------- weight prep ----------------------------------------------
__global__ __launch_bounds__(256) void wd_transpose_kernel(const float* __restrict__ Wd,
                                                           u16* __restrict__ WdT) {
  __shared__ float tbuf[32][33];
  int tx = threadIdx.x & 31, ty = threadIdx.x >> 5;
  int ot = blockIdx.x * 32, dt = blockIdx.y * 32;
  #pragma unroll
  for (int j = 0; j < 4; ++j) {
    int o = ot + ty + 8 * j, d = dt + tx;
    tbuf[ty + 8 * j][tx] = (o < 1026 && d < 1026) ? Wd[(size_t)o * 1026 + d] : 0.f;
  }
  __syncthreads();
  #pragma unroll
  for (int j = 0; j < 4; ++j) {
    int d = dt + ty + 8 * j, o = ot + tx;
    if (o < KP) WdT[(size_t)d * KP + o] = f2bf(tbuf[tx][ty + 8 * j]);
  }
}

__global__ __launch_bounds__(256) void wagg_convert_kernel(const float* __restrict__ Wagg,
                                                           u16* __restrict__ Wa1,
                                                           u16* __restrict__ Wa2) {
  int c = blockIdx.x, t = threadIdx.x;
  const float* row = Wagg + (size_t)c * 2052;
  for (int d = t; d < KP; d += 256) {
    Wa1[(size_t)c * KP + d] = (d < 1026) ? f2bf(row[d]) : (u16)0;
    Wa2[(size_t)c * KP + d] = (d < 1026) ? f2bf(row[1026 + d]) : (u16)0;
  }
}

__global__ __launch_bounds__(256) void czero_kernel(const float* __restrict__ bdiff,
                                                    const float* __restrict__ Wagg,
                                                    const float* __restrict__ bagg,
                                                    float* __restrict__ czero) {
  int lane = threadIdx.x & 63, wv = threadIdx.x >> 6;
  int c = blockIdx.x * 4 + wv;
  float acc = 0.f;
  for (int o = lane; o < 1026; o += 64) acc += bdiff[o] * Wagg[(size_t)c * 2052 + o];
  acc = wave_sum64(acc);
  if (lane == 0) czero[c] = acc + bagg[c];
}

// ---------------- bf16 MFMA GEMM: C[M,N] = A[M,K] @ Bt[N,K]^T ---------------
template <int BF16OUT>
__global__ __launch_bounds__(256) void gemm_bt_kernel(const u16* __restrict__ A,
                                                      const u16* __restrict__ Bt,
                                                      void* __restrict__ Cout,
                                                      int M, int N, int K, int ldc, int nvalid) {
  __shared__ __align__(16) u16 As[128 * 32];
  __shared__ __align__(16) u16 Bs[128 * 32];
  const int tid = threadIdx.x;
  const int lane = tid & 63;
  const int wv = tid >> 6;
  const int m0 = blockIdx.y * 128;
  const int n0 = blockIdx.x * 128;
  const int wm = (wv >> 1) * 64;
  const int wn = (wv & 1) * 64;

  f32x4 acc[4][4];
  #pragma unroll
  for (int i = 0; i < 4; ++i)
    #pragma unroll
    for (int j = 0; j < 4; ++j)
      #pragma unroll
      for (int c = 0; c < 4; ++c) acc[i][j][c] = 0.f;

  const int ch0 = wv * 2;
  const int rin = lane >> 2;        // row within 16-row chunk
  const int cin = (lane & 3) * 8;   // u16 col offset

  for (int k0 = 0; k0 < K; k0 += 32) {
    #pragma unroll
    for (int i = 0; i < 2; ++i) {
      const int ch = ch0 + i;
      const int row = ch * 16 + rin;
      const u16* ga = A + (size_t)(m0 + row) * K + (k0 + cin);
      const u16* gb = Bt + (size_t)(n0 + row) * K + (k0 + cin);
      __builtin_amdgcn_global_load_lds((gvp)ga, (svp)(As + ch * 512), 16, 0, 0);
      __builtin_amdgcn_global_load_lds((gvp)gb, (svp)(Bs + ch * 512), 16, 0, 0);
    }
    __syncthreads();
    const int rf = lane & 15;
    const int qf = (lane >> 4) * 8;
    bf16x8 af[4], bfv[4];
    #pragma unroll
    for (int mi = 0; mi < 4; ++mi)
      af[mi] = *(const bf16x8*)(As + (wm + mi * 16 + rf) * 32 + qf);
    #pragma unroll
    for (int ni = 0; ni < 4; ++ni)
      bfv[ni] = *(const bf16x8*)(Bs + (wn + ni * 16 + rf) * 32 + qf);
    #pragma unroll
    for (int mi = 0; mi < 4; ++mi)
      #pragma unroll
      for (int ni = 0; ni < 4; ++ni)
        acc[mi][ni] = __builtin_amdgcn_mfma_f32_16x16x32_bf16(af[mi], bfv[ni], acc[mi][ni], 0, 0, 0);
    __syncthreads();
  }

  const int rq = (lane >> 4) * 4;
  const int cf = lane & 15;
  #pragma unroll
  for (int mi = 0; mi < 4; ++mi) {
    #pragma unroll
    for (int ni = 0; ni < 4; ++ni) {
      const int col = n0 + wn + ni * 16 + cf;
      #pragma unroll
      for (int r = 0; r < 4; ++r) {
        const int row = m0 + wm + mi * 16 + rq + r;
        const float v = acc[mi][ni][r];
        if (BF16OUT) {
          if (col < nvalid) ((u16*)Cout)[(size_t)row * ldc + col] = f2bf(v);
        } else {
          ((float*)Cout)[(size_t)row * ldc + col] = v;
        }
      }
    }
  }
}

// ---------------- fused gather + relu + LN + mean_k -------------------------
template <int BF16OUT>
__global__ __launch_bounds__(256) void h_epilogue_kernel(const float* __restrict__ Z1,
                                                         const float* __restrict__ Z2g,
                                                         const float* __restrict__ czero,
                                                         const int* __restrict__ idxK,
                                                         const int* __restrict__ fi,
                                                         const float* __restrict__ g,
                                                         const float* __restrict__ bb,
                                                         const float* __restrict__ npts,
                                                         void* __restrict__ outp,
                                                         int Np, int S) {
  __shared__ float r1[4];
  __shared__ float r2[4];
  int q = blockIdx.x;
  int b = q / S;
  int t = threadIdx.x;
  int lane = t & 63, wv = t >> 6;
  int fiv = fi[q];
  const f32x4* z2 = (const f32x4*)(Z2g + (size_t)q * 1024);
  const f32x4* zf = (const f32x4*)(Z1 + ((size_t)b * Np + fiv) * 1024);
  const f32x4* cz = (const f32x4*)czero;
  f32x4 base = z2[t] + cz[t] - zf[t];
  f32x4 gv = ((const f32x4*)g)[t];
  f32x4 bv = ((const f32x4*)bb)[t];
  f32x4 acc;
  #pragma unroll
  for (int c = 0; c < 4; ++c) acc[c] = 0.f;
  for (int k = 0; k < 24; ++k) {
    int n = idxK[(size_t)q * 24 + k];
    const f32x4* zr = (const f32x4*)(Z1 + ((size_t)b * Np + n) * 1024);
    f32x4 v = zr[t] + base;
    #pragma unroll
    for (int c = 0; c < 4; ++c) v[c] = fmaxf(v[c], 0.f);
    float s1 = v[0] + v[1] + v[2] + v[3];
    float s2 = v[0] * v[0] + v[1] * v[1] + v[2] * v[2] + v[3] * v[3];
    #pragma unroll
    for (int off = 32; off; off >>= 1) {
      s1 += __shfl_xor(s1, off);
      s2 += __shfl_xor(s2, off);
    }
    if (lane == 0) { r1[wv] = s1; r2[wv] = s2; }
    __syncthreads();
    s1 = r1[0] + r1[1] + r1[2] + r1[3];
    s2 = r2[0] + r2[1] + r2[2] + r2[3];
    __syncthreads();
    float m = s1 * (1.f / 1024.f);
    float var = s2 * (1.f / 1024.f) - m * m;
    float rs = rsqrtf(var + 1e-5f);
    #pragma unroll
    for (int c = 0; c < 4; ++c) acc[c] += (v[c] - m) * rs * gv[c] + bv[c];
  }
  #pragma unroll
  for (int c = 0; c < 4; ++c) acc[c] *= (1.f / 24.f);
  if (BF16OUT) {
    u16* X = (u16*)outp;
    size_t ro = (size_t)q * KP;
    u16x4 o4;
    #pragma unroll
    for (int c = 0; c < 4; ++c) o4[c] = f2bf(acc[c]);
    *(u16x4*)(X + ro + t * 4) = o4;
    if (t == 0) {
      X[ro + 1024] = f2bf(npts[(size_t)q * 2]);
      X[ro + 1025] = f2bf(npts[(size_t)q * 2 + 1]);
    }
    if (t < 15) ((u32*)(X + ro + 1026))[t] = 0;
  } else {
    ((f32x4*)outp)[(size_t)q * 256 + t] = acc;
  }
}

// ---------------- final fp32 GEMMs: register-tiled, coalesced ---------------
// x1[b,o] = bflat[o] + sum_k fea2[b,k]*Wflat[o,k]
// Wave owns 4 weight rows; lanes partition K (float4); fea2 chunk in LDS.
__global__ __launch_bounds__(256) void x1_init_kernel(const float* __restrict__ bflat,
                                                      float* __restrict__ x1) {
  int i = blockIdx.x * 256 + threadIdx.x;  // 32768
  x1[i] = bflat[i & 1023];
}

// grid 512 = (o-tile:64) x (k-split:8); block 256 = 4 waves x 4 o each
__global__ __launch_bounds__(256, 2) void flat_gemm_kernel(const float* __restrict__ fea2,
                                                           const float* __restrict__ Wf,
                                                           float* __restrict__ x1) {
  __shared__ __align__(16) float Ft[32][260];  // 260: keeps f32x4 alignment per row
  const int tid = threadIdx.x, lane = tid & 63, wv = tid >> 6;
  const int ot = blockIdx.x >> 3;   // 0..63
  const int ks = blockIdx.x & 7;    // 0..7
  const int obase = ot * 16 + wv * 4;
  const int kbase = ks * 4096;

  float acc[4][32];
  #pragma unroll
  for (int oi = 0; oi < 4; ++oi)
    #pragma unroll
    for (int b = 0; b < 32; ++b) acc[oi][b] = 0.f;

  const f32x4* wp[4];
  #pragma unroll
  for (int oi = 0; oi < 4; ++oi)
    wp[oi] = (const f32x4*)(Wf + (size_t)(obase + oi) * 32768 + kbase) + lane;

  for (int it = 0; it < 16; ++it) {
    const int kb = kbase + it * 256;
    #pragma unroll
    for (int j = 0; j < 8; ++j) {
      int idx = j * 256 + tid;          // 0..2047 float4s
      int r = idx >> 6, c = idx & 63;
      *(f32x4*)&Ft[r][c * 4] = *(const f32x4*)(fea2 + (size_t)r * 32768 + kb + c * 4);
    }
    f32x4 wreg[4];
    #pragma unroll
    for (int oi = 0; oi < 4; ++oi) wreg[oi] = wp[oi][it * 64];
    __syncthreads();
    #pragma unroll
    for (int b = 0; b < 32; ++b) {
      f32x4 f = *(const f32x4*)&Ft[b][lane * 4];
      #pragma unroll
      for (int oi = 0; oi < 4; ++oi)
        #pragma unroll
        for (int c = 0; c < 4; ++c) acc[oi][b] += wreg[oi][c] * f[c];
    }
    __syncthreads();
  }

  #pragma unroll
  for (int oi = 0; oi < 4; ++oi)
    #pragma unroll
    for (int b = 0; b < 32; ++b) acc[oi][b] = wave_sum64(acc[oi][b]);
  if (lane < 32) {
    #pragma unroll
    for (int oi = 0; oi < 4; ++oi)
      atomicAdd(&x1[lane * 1024 + obase + oi], acc[oi][lane]);
  }
}

// grid 256 = o-tiles; block 256 = 4 waves x 4 o each; K=1024, no split
__global__ __launch_bounds__(256, 2) void dim_gemm_kernel(const float* __restrict__ x1,
                                                          const float* __restrict__ Wd,
                                                          const float* __restrict__ bdim,
                                                          float* __restrict__ out) {
  __shared__ __align__(16) float Ft[32][260];
  const int tid = threadIdx.x, lane = tid & 63, wv = tid >> 6;
  const int obase = blockIdx.x * 16 + wv * 4;

  float acc[4][32];
  #pragma unroll
  for (int oi = 0; oi < 4; ++oi)
    #pragma unroll
    for (int b = 0; b < 32; ++b) acc[oi][b] = 0.f;

  const f32x4* wp[4];
  #pragma unroll
  for (int oi = 0; oi < 4; ++oi)
    wp[oi] = (const f32x4*)(Wd + (size_t)(obase + oi) * 1024) + lane;

  for (int it = 0; it < 4; ++it) {
    const int kb = it * 256;
    #pragma unroll
    for (int j = 0; j < 8; ++j) {
      int idx = j * 256 + tid;
      int r = idx >> 6, c = idx & 63;
      *(f32x4*)&Ft[r][c * 4] = *(const f32x4*)(x1 + (size_t)r * 1024 + kb + c * 4);
    }
    f32x4 wreg[4];
    #pragma unroll
    for (int oi = 0; oi < 4; ++oi) wreg[oi] = wp[oi][it * 64];
    __syncthreads();
    #pragma unroll
    for (int b = 0; b < 32; ++b) {
      f32x4 f = *(const f32x4*)&Ft[b][lane * 4];
      #pragma unroll
      for (int oi = 0; oi < 4; ++oi)
        #pragma unroll
        for (int c = 0; c < 4; ++c) acc[oi][b] += wreg[oi][c] * f[c];
    }
    __syncthreads();
  }

  #pragma unroll
  for (int oi = 0; oi < 4; ++oi)
    #pragma unroll
    for (int b = 0; b < 32; ++b) acc[oi][b] = wave_sum64(acc[oi][b]);
  if (lane < 32) {
    #pragma unroll
    for (int oi = 0; oi < 4; ++oi)
      out[(size_t)lane * 4096 + obase + oi] = acc[oi][lane] + bdim[obase + oi];
  }
}

// ---------------------------------------------------------------------------
extern "C" void kernel_launch(void* const* d_in, const int* in_sizes, int n_in,
                              void* d_out, int out_size, void* d_ws, size_t ws_size,
                              hipStream_t stream) {
  const float* fmap  = (const float*)d_in[0];
  const float* pts   = (const float*)d_in[1];
  const float* Wdiff = (const float*)d_in[2];
  const float* bdiff = (const float*)d_in[3];
  const float* Wagg  = (const float*)d_in[4];
  const float* bagg  = (const float*)d_in[5];
  const float* lng   = (const float*)d_in[6];
  const float* lnb   = (const float*)d_in[7];
  const float* Wflat = (const float*)d_in[8];
  const float* bflat = (const float*)d_in[9];
  const float* Wdim  = (const float*)d_in[10];
  const float* bdim  = (const float*)d_in[11];
  float* out = (float*)d_out;

  char* w = (char*)d_ws;
  size_t off = 0;
  auto alloc = [&](size_t n) { char* p = w + off; off += (n + 255) & ~(size_t)255; return p; };

  float* Z1    = (float*)alloc(16384ull * 1024 * 4);  // 67.1 MB (stage0/1 reuse)
  float* Z2g   = (float*)alloc(4096ull * 1024 * 4);   // 16.8 MB
  float* fmapT = Z1;  // alias: fmapT (75.5 MB) dead before any Z write
  u16* Xbf0  = (u16*)alloc(16384ull * KP * 2);
  u16* X1bf  = (u16*)alloc(4096ull * KP * 2);
  u16* Xg    = (u16*)alloc(4096ull * KP * 2);
  u16* WdT   = (u16*)alloc((size_t)NP0 * KP * 2);
  u16* Wa1   = (u16*)alloc(1024ull * KP * 2);
  u16* Wa2   = (u16*)alloc(1024ull * KP * 2);
  u16* Wcomb = (u16*)alloc(1024ull * KP * 2);
  float* czero = (float*)alloc(1024 * 4);
  int* fi0   = (int*)alloc(32 * 128 * 4);
  int* fi1   = (int*)alloc(32 * 32 * 4);
  int* idx0  = (int*)alloc(32 * 128 * 24 * 4);
  int* idx1  = (int*)alloc(32 * 32 * 24 * 4);
  float* npts0 = (float*)alloc(32 * 128 * 2 * 4);
  float* npts1 = (float*)alloc(32 * 32 * 2 * 4);
  float* fea2  = (float*)alloc(32ull * 32 * 1024 * 4);
  float* x1    = (float*)alloc(32 * 1024 * 4);

  // ---- stage-0 inputs
  fmap_transpose_kernel<<<dim3(18, 32, 32), 256, 0, stream>>>(fmap, fmapT);
  bilinear_kernel<<<16384, 256, 0, stream>>>(fmapT, pts, Xbf0);

  // ---- stage 0 (Np=512, S=128)
  fps_kernel<8><<<32, 64, 0, stream>>>(pts, fi0, 512, 128);
  gather_fi_kernel<<<4096, 128, 0, stream>>>(Xbf0, pts, fi0, Xg, npts0, 512, 128);
  knn_kernel<8><<<1024, 256, 0, stream>>>(npts0, pts, idx0, 512, 128);
  wd_transpose_kernel<<<dim3(33, 36), 256, 0, stream>>>(Wdiff, WdT);
  wagg_convert_kernel<<<1024, 256, 0, stream>>>(Wagg, Wa1, Wa2);
  czero_kernel<<<256, 256, 0, stream>>>(bdiff, Wagg, bagg, czero);
  gemm_bt_kernel<1><<<dim3(9, 8), 256, 0, stream>>>(Wa1, WdT, Wcomb, 1024, NP0, KP, KP, KP);
  gemm_bt_kernel<0><<<dim3(8, 128), 256, 0, stream>>>(Xbf0, Wcomb, Z1, 16384, 1024, KP, 1024, 1024);
  gemm_bt_kernel<0><<<dim3(8, 32), 256, 0, stream>>>(Xg, Wa2, Z2g, 4096, 1024, KP, 1024, 1024);
  h_epilogue_kernel<1><<<4096, 256, 0, stream>>>(Z1, Z2g, czero, idx0, fi0, lng, lnb, npts0,
                                                 X1bf, 512, 128);

  // ---- stage 1 (Np=128, S=32)
  fps_kernel<2><<<32, 64, 0, stream>>>(npts0, fi1, 128, 32);
  gather_fi_kernel<<<1024, 128, 0, stream>>>(X1bf, npts0, fi1, Xg, npts1, 128, 32);
  knn_kernel<2><<<256, 256, 0, stream>>>(npts1, npts0, idx1, 128, 32);
  wd_transpose_kernel<<<dim3(33, 36), 256, 0, stream>>>(Wdiff + 1026 * 1026, WdT);
  wagg_convert_kernel<<<1024, 256, 0, stream>>>(Wagg + 1024 * 2052, Wa1, Wa2);
  czero_kernel<<<256, 256, 0, stream>>>(bdiff + 1026, Wagg + 1024 * 2052, bagg + 1024, czero);
  gemm_bt_kernel<1><<<dim3(9, 8), 256, 0, stream>>>(Wa1, WdT, Wcomb, 1024, NP0, KP, KP, KP);
  gemm_bt_kernel<0><<<dim3(8, 32), 256, 0, stream>>>(X1bf, Wcomb, Z1, 4096, 1024, KP, 1024, 1024);
  gemm_bt_kernel<0><<<dim3(8, 8), 256, 0, stream>>>(Xg, Wa2, Z2g, 1024, 1024, KP, 1024, 1024);
  h_epilogue_kernel<0><<<1024, 256, 0, stream>>>(Z1, Z2g, czero, idx1, fi1, lng + 1024, lnb + 1024,
                                                 npts1, fea2, 128, 32);

  // ---- final MLP
  x1_init_kernel<<<128, 256, 0, stream>>>(bflat, x1);
  flat_gemm_kernel<<<512, 256, 0, stream>>>(fea2, Wflat, x1);
  dim_gemm_kernel<<<256, 256, 0, stream>>>(x1, Wdim, bdim, out);
}

// Round 3
// 1009.754 us; speedup vs baseline: 1.4042x; 1.1006x over previous
//
#include <hip/hip_runtime.h>

// ---------------------------------------------------------------------------
// GeoRegionSampler: restructured pipeline
//   X = [bilinear_fea | pts] (bf16, padded 1026->1056); bilinear fused with
//   fmap channel-tile staging in LDS (no transpose round-trip).
//   Wcomb = Wa1 @ Wd   (bf16 MFMA GEMM)
//   Z1 = X @ Wcomb^T ; Z2 = X[fi] @ Wa2^T ; czero = b_diff@Wa1^T + b_agg
//   h[b,s,k] = relu(Z1[idx]-Z1[fi]+Z2[s]+czero) -> LN -> mean_k  (fused)
//   final fp32 GEMMs: lane=(bg,kg) decomposition, acc[8o][4b]=32 VGPR
//   (R2's acc[4][32]=128 spilled -> 1.2 GB scratch writes; this is the fix)
// FPS/kNN: fp32 bit-exact (fp contract off), first-index tie-break.
// ---------------------------------------------------------------------------

typedef float f32x4 __attribute__((ext_vector_type(4)));
typedef short bf16x8 __attribute__((ext_vector_type(8)));
typedef unsigned short u16;
typedef u16 u16x4 __attribute__((ext_vector_type(4)));
typedef unsigned int u32;
typedef u32 u32x4 __attribute__((ext_vector_type(4)));

typedef const void __attribute__((address_space(1)))* gvp;
typedef void __attribute__((address_space(3)))* svp;

__device__ __forceinline__ u16 f2bf(float f) {
  union { float f; u32 u; } x; x.f = f;
  u32 r = x.u + 0x7fffu + ((x.u >> 16) & 1u);
  return (u16)(r >> 16);
}

#define KP 1056   // padded Dp (1026 -> 33*32)
#define NP0 1152  // padded N for weight-combine GEMM (9*128)

// ------- fused bilinear: stage fmap[b][ct*32..+31][:] in LDS, interp -------
__global__ __launch_bounds__(256, 2) void bilinear_fused_kernel(const float* __restrict__ fmap,
                                                                const float* __restrict__ pts,
                                                                u16* __restrict__ X) {
  __shared__ float fmS[32][580];  // 580: f32x4-aligned, stride%32=4 rotates banks
  const int ct = blockIdx.x, b = blockIdx.y;
  const int t = threadIdx.x;
  const float* src = fmap + ((size_t)b * 1024 + ct * 32) * 576;
  const int tr = t >> 3, ti = t & 7;  // 32 rows x 8 threads/row
  #pragma unroll
  for (int j = 0; j < 18; ++j) {
    int c4 = j * 8 + ti;  // 0..143 f32x4 per row
    *(f32x4*)&fmS[tr][c4 * 4] = *(const f32x4*)(src + (size_t)tr * 576 + c4 * 4);
  }
  __syncthreads();
  #pragma unroll
  for (int pass = 0; pass < 2; ++pass) {
    const int n = pass * 256 + t;
    const int pidx = b * 512 + n;
    float p0 = pts[(size_t)pidx * 2], p1 = pts[(size_t)pidx * 2 + 1];
    float gy = p0 * 23.f, gx = p1 * 23.f;
    float y0f = floorf(gy), x0f = floorf(gx);
    float wy = gy - y0f, wx = gx - x0f;
    int y0 = (int)y0f; y0 = y0 < 0 ? 0 : (y0 > 23 ? 23 : y0);
    int x0 = (int)x0f; x0 = x0 < 0 ? 0 : (x0 > 23 ? 23 : x0);
    int y1 = y0 + 1 > 23 ? 23 : y0 + 1;
    int x1 = x0 + 1 > 23 ? 23 : x0 + 1;
    float w00 = (1.f - wy) * (1.f - wx), w01 = (1.f - wy) * wx;
    float w10 = wy * (1.f - wx), w11 = wy * wx;
    const int i00 = y0 * 24 + x0, i01 = y0 * 24 + x1;
    const int i10 = y1 * 24 + x0, i11 = y1 * 24 + x1;
    size_t ro = (size_t)pidx * KP + ct * 32;
    #pragma unroll
    for (int cq = 0; cq < 8; ++cq) {
      u16x4 o4;
      #pragma unroll
      for (int cc = 0; cc < 4; ++cc) {
        int c = cq * 4 + cc;
        float v = w00 * fmS[c][i00] + w01 * fmS[c][i01] +
                  w10 * fmS[c][i10] + w11 * fmS[c][i11];
        o4[cc] = f2bf(v);
      }
      *(u16x4*)(X + ro + cq * 4) = o4;
    }
    if (ct == 31) {
      size_t rb = (size_t)pidx * KP;
      X[rb + 1024] = f2bf(p0);
      X[rb + 1025] = f2bf(p1);
      #pragma unroll
      for (int z = 0; z < 15; ++z) ((u32*)(X + rb + 1026))[z] = 0;
    }
  }
}

// ---------------- FPS: one wave per batch, bit-exact ------------------------
template <int PPL>
__global__ void fps_kernel(const float* __restrict__ pts, int* __restrict__ fi,
                           int Np, int S) {
  #pragma clang fp contract(off)
  int b = blockIdx.x;
  int lane = threadIdx.x;
  float px[PPL], py[PPL], dist[PPL];
  #pragma unroll
  for (int j = 0; j < PPL; ++j) {
    int n = j * 64 + lane;
    px[j] = pts[((size_t)b * Np + n) * 2];
    py[j] = pts[((size_t)b * Np + n) * 2 + 1];
    dist[j] = 1e10f;
  }
  int far = 0;
  for (int s = 0; s < S; ++s) {
    if (lane == 0) fi[b * S + s] = far;
    float cx = pts[((size_t)b * Np + far) * 2];
    float cy = pts[((size_t)b * Np + far) * 2 + 1];
    float bv = -1.f; int bi = 0;
    #pragma unroll
    for (int j = 0; j < PPL; ++j) {
      float dx = px[j] - cx, dy = py[j] - cy;
      float d = dx * dx + dy * dy;
      float nd = fminf(dist[j], d);
      dist[j] = nd;
      if (nd > bv) { bv = nd; bi = j * 64 + lane; }
    }
    #pragma unroll
    for (int off = 32; off; off >>= 1) {
      float ov = __shfl_xor(bv, off);
      int oi = __shfl_xor(bi, off);
      if (ov > bv || (ov == bv && oi < bi)) { bv = ov; bi = oi; }
    }
    far = bi;
  }
}

// ---------------- kNN: one wave per (b,s), bit-exact ------------------------
template <int PPL>
__global__ __launch_bounds__(256) void knn_kernel(const float* __restrict__ qpts,
                                                  const float* __restrict__ rpts,
                                                  int* __restrict__ idxK, int Np, int S) {
  #pragma clang fp contract(off)
  int lane = threadIdx.x & 63, wv = threadIdx.x >> 6;
  int q = blockIdx.x * 4 + wv;
  int b = q / S;
  float ax = qpts[(size_t)q * 2], ay = qpts[(size_t)q * 2 + 1];
  float a2 = ax * ax + ay * ay;
  float d2[PPL];
  #pragma unroll
  for (int j = 0; j < PPL; ++j) {
    int n = j * 64 + lane;
    float bx = rpts[((size_t)b * Np + n) * 2];
    float by = rpts[((size_t)b * Np + n) * 2 + 1];
    float b2 = bx * bx + by * by;
    float dot = ax * bx + ay * by;
    float t = a2 + b2;
    float m2 = 2.f * dot;
    d2[j] = t - m2;
  }
  for (int k = 0; k < 24; ++k) {
    float bv = 3.4e38f; int bi = 1 << 30;
    #pragma unroll
    for (int j = 0; j < PPL; ++j)
      if (d2[j] < bv) { bv = d2[j]; bi = j * 64 + lane; }
    #pragma unroll
    for (int off = 32; off; off >>= 1) {
      float ov = __shfl_xor(bv, off);
      int oi = __shfl_xor(bi, off);
      if (ov < bv || (ov == bv && oi < bi)) { bv = ov; bi = oi; }
    }
    if (lane == 0) idxK[(size_t)q * 24 + k] = bi;
    #pragma unroll
    for (int j = 0; j < PPL; ++j)
      if (j * 64 + lane == bi) d2[j] = 3.4e38f;
  }
}

// ---------------- gather X rows at fi; emit new_pts -------------------------
__global__ __launch_bounds__(128) void gather_fi_kernel(const u16* __restrict__ Xsrc,
                                                        const float* __restrict__ pts,
                                                        const int* __restrict__ fi,
                                                        u16* __restrict__ Xg,
                                                        float* __restrict__ npts,
                                                        int Np, int S) {
  int q = blockIdx.x;
  int b = q / S;
  int t = threadIdx.x;
  int r = fi[q];
  const u32x4* src = (const u32x4*)(Xsrc + ((size_t)b * Np + r) * KP);
  u32x4* dst = (u32x4*)(Xg + (size_t)q * KP);
  dst[t] = src[t];
  int t2 = t + 128;
  if (t2 < 132) dst[t2] = src[t2];
  if (t == 0) {
    npts[(size_t)q * 2] = pts[((size_t)b * Np + r) * 2];
    npts[(size_t)q * 2 + 1] = pts[((size_t)b * Np + r) * 2 + 1];
  }
}

// ---------------- weight prep ----------------------------------------------
__global__ __launch_bounds__(256) void wd_transpose_kernel(const float* __restrict__ Wd,
                                                           u16* __restrict__ WdT) {
  __shared__ float tbuf[32][33];
  int tx = threadIdx.x & 31, ty = threadIdx.x >> 5;
  int ot = blockIdx.x * 32, dt = blockIdx.y * 32;
  #pragma unroll
  for (int j = 0; j < 4; ++j) {
    int o = ot + ty + 8 * j, d = dt + tx;
    tbuf[ty + 8 * j][tx] = (o < 1026 && d < 1026) ? Wd[(size_t)o * 1026 + d] : 0.f;
  }
  __syncthreads();
  #pragma unroll
  for (int j = 0; j < 4; ++j) {
    int d = dt + ty + 8 * j, o = ot + tx;
    if (o < KP) WdT[(size_t)d * KP + o] = f2bf(tbuf[tx][ty + 8 * j]);
  }
}

__global__ __launch_bounds__(256) void wagg_convert_kernel(const float* __restrict__ Wagg,
                                                           u16* __restrict__ Wa1,
                                                           u16* __restrict__ Wa2) {
  int c = blockIdx.x, t = threadIdx.x;
  const float* row = Wagg + (size_t)c * 2052;
  for (int d = t; d < KP; d += 256) {
    Wa1[(size_t)c * KP + d] = (d < 1026) ? f2bf(row[d]) : (u16)0;
    Wa2[(size_t)c * KP + d] = (d < 1026) ? f2bf(row[1026 + d]) : (u16)0;
  }
}

__global__ __launch_bounds__(256) void czero_kernel(const float* __restrict__ bdiff,
                                                    const float* __restrict__ Wagg,
                                                    const float* __restrict__ bagg,
                                                    float* __restrict__ czero) {
  int lane = threadIdx.x & 63, wv = threadIdx.x >> 6;
  int c = blockIdx.x * 4 + wv;
  float acc = 0.f;
  for (int o = lane; o < 1026; o += 64) acc += bdiff[o] * Wagg[(size_t)c * 2052 + o];
  #pragma unroll
  for (int off = 32; off; off >>= 1) acc += __shfl_xor(acc, off);
  if (lane == 0) czero[c] = acc + bagg[c];
}

// ---------------- bf16 MFMA GEMM: C[M,N] = A[M,K] @ Bt[N,K]^T ---------------
template <int BF16OUT>
__global__ __launch_bounds__(256) void gemm_bt_kernel(const u16* __restrict__ A,
                                                      const u16* __restrict__ Bt,
                                                      void* __restrict__ Cout,
                                                      int M, int N, int K, int ldc, int nvalid) {
  __shared__ __align__(16) u16 As[128 * 32];
  __shared__ __align__(16) u16 Bs[128 * 32];
  const int tid = threadIdx.x;
  const int lane = tid & 63;
  const int wv = tid >> 6;
  const int m0 = blockIdx.y * 128;
  const int n0 = blockIdx.x * 128;
  const int wm = (wv >> 1) * 64;
  const int wn = (wv & 1) * 64;

  f32x4 acc[4][4];
  #pragma unroll
  for (int i = 0; i < 4; ++i)
    #pragma unroll
    for (int j = 0; j < 4; ++j)
      #pragma unroll
      for (int c = 0; c < 4; ++c) acc[i][j][c] = 0.f;

  const int ch0 = wv * 2;
  const int rin = lane >> 2;        // row within 16-row chunk
  const int cin = (lane & 3) * 8;   // u16 col offset

  for (int k0 = 0; k0 < K; k0 += 32) {
    #pragma unroll
    for (int i = 0; i < 2; ++i) {
      const int ch = ch0 + i;
      const int row = ch * 16 + rin;
      const u16* ga = A + (size_t)(m0 + row) * K + (k0 + cin);
      const u16* gb = Bt + (size_t)(n0 + row) * K + (k0 + cin);
      __builtin_amdgcn_global_load_lds((gvp)ga, (svp)(As + ch * 512), 16, 0, 0);
      __builtin_amdgcn_global_load_lds((gvp)gb, (svp)(Bs + ch * 512), 16, 0, 0);
    }
    __syncthreads();
    const int rf = lane & 15;
    const int qf = (lane >> 4) * 8;
    bf16x8 af[4], bfv[4];
    #pragma unroll
    for (int mi = 0; mi < 4; ++mi)
      af[mi] = *(const bf16x8*)(As + (wm + mi * 16 + rf) * 32 + qf);
    #pragma unroll
    for (int ni = 0; ni < 4; ++ni)
      bfv[ni] = *(const bf16x8*)(Bs + (wn + ni * 16 + rf) * 32 + qf);
    #pragma unroll
    for (int mi = 0; mi < 4; ++mi)
      #pragma unroll
      for (int ni = 0; ni < 4; ++ni)
        acc[mi][ni] = __builtin_amdgcn_mfma_f32_16x16x32_bf16(af[mi], bfv[ni], acc[mi][ni], 0, 0, 0);
    __syncthreads();
  }

  const int rq = (lane >> 4) * 4;
  const int cf = lane & 15;
  #pragma unroll
  for (int mi = 0; mi < 4; ++mi) {
    #pragma unroll
    for (int ni = 0; ni < 4; ++ni) {
      const int col = n0 + wn + ni * 16 + cf;
      #pragma unroll
      for (int r = 0; r < 4; ++r) {
        const int row = m0 + wm + mi * 16 + rq + r;
        const float v = acc[mi][ni][r];
        if (BF16OUT) {
          if (col < nvalid) ((u16*)Cout)[(size_t)row * ldc + col] = f2bf(v);
        } else {
          ((float*)Cout)[(size_t)row * ldc + col] = v;
        }
      }
    }
  }
}

// ---------------- fused gather + relu + LN + mean_k -------------------------
template <int BF16OUT>
__global__ __launch_bounds__(256) void h_epilogue_kernel(const float* __restrict__ Z1,
                                                         const float* __restrict__ Z2g,
                                                         const float* __restrict__ czero,
                                                         const int* __restrict__ idxK,
                                                         const int* __restrict__ fi,
                                                         const float* __restrict__ g,
                                                         const float* __restrict__ bb,
                                                         const float* __restrict__ npts,
                                                         void* __restrict__ outp,
                                                         int Np, int S) {
  __shared__ float r1[4];
  __shared__ float r2[4];
  int q = blockIdx.x;
  int b = q / S;
  int t = threadIdx.x;
  int lane = t & 63, wv = t >> 6;
  int fiv = fi[q];
  const f32x4* z2 = (const f32x4*)(Z2g + (size_t)q * 1024);
  const f32x4* zf = (const f32x4*)(Z1 + ((size_t)b * Np + fiv) * 1024);
  const f32x4* cz = (const f32x4*)czero;
  f32x4 base = z2[t] + cz[t] - zf[t];
  f32x4 gv = ((const f32x4*)g)[t];
  f32x4 bv = ((const f32x4*)bb)[t];
  f32x4 acc;
  #pragma unroll
  for (int c = 0; c < 4; ++c) acc[c] = 0.f;
  for (int k = 0; k < 24; ++k) {
    int n = idxK[(size_t)q * 24 + k];
    const f32x4* zr = (const f32x4*)(Z1 + ((size_t)b * Np + n) * 1024);
    f32x4 v = zr[t] + base;
    #pragma unroll
    for (int c = 0; c < 4; ++c) v[c] = fmaxf(v[c], 0.f);
    float s1 = v[0] + v[1] + v[2] + v[3];
    float s2 = v[0] * v[0] + v[1] * v[1] + v[2] * v[2] + v[3] * v[3];
    #pragma unroll
    for (int off = 32; off; off >>= 1) {
      s1 += __shfl_xor(s1, off);
      s2 += __shfl_xor(s2, off);
    }
    if (lane == 0) { r1[wv] = s1; r2[wv] = s2; }
    __syncthreads();
    s1 = r1[0] + r1[1] + r1[2] + r1[3];
    s2 = r2[0] + r2[1] + r2[2] + r2[3];
    __syncthreads();
    float m = s1 * (1.f / 1024.f);
    float var = s2 * (1.f / 1024.f) - m * m;
    float rs = rsqrtf(var + 1e-5f);
    #pragma unroll
    for (int c = 0; c < 4; ++c) acc[c] += (v[c] - m) * rs * gv[c] + bv[c];
  }
  #pragma unroll
  for (int c = 0; c < 4; ++c) acc[c] *= (1.f / 24.f);
  if (BF16OUT) {
    u16* X = (u16*)outp;
    size_t ro = (size_t)q * KP;
    u16x4 o4;
    #pragma unroll
    for (int c = 0; c < 4; ++c) o4[c] = f2bf(acc[c]);
    *(u16x4*)(X + ro + t * 4) = o4;
    if (t == 0) {
      X[ro + 1024] = f2bf(npts[(size_t)q * 2]);
      X[ro + 1025] = f2bf(npts[(size_t)q * 2 + 1]);
    }
    if (t < 15) ((u32*)(X + ro + 1026))[t] = 0;
  } else {
    ((f32x4*)outp)[(size_t)q * 256 + t] = acc;
  }
}

// ---------------- final fp32 GEMMs v3: lane=(bg,kg), acc[8o][4b] ------------
// x1[b,o] = bflat[o] + sum_k fea2[b,k]*Wflat[o,k]
__global__ __launch_bounds__(256) void x1_init_kernel(const float* __restrict__ bflat,
                                                      float* __restrict__ x1) {
  int i = blockIdx.x * 256 + threadIdx.x;  // 32768
  x1[i] = bflat[i & 1023];
}

__global__ __launch_bounds__(256) void out_init_kernel(const float* __restrict__ bdim,
                                                       float* __restrict__ out) {
  int i = blockIdx.x * 256 + threadIdx.x;  // 131072
  out[i] = bdim[i & 4095];
}

// grid 1024 = 32 o-tiles x 32 k-splits; block 256 = 4 waves x 8 o each
// lane: kg=lane&7 partitions K (f32x4), bg=lane>>3 picks 4 batches b=bg*4+j
__global__ __launch_bounds__(256, 4) void flat_gemm_kernel(const float* __restrict__ fea2,
                                                           const float* __restrict__ Wf,
                                                           float* __restrict__ x1) {
  __shared__ __align__(16) float Ft[32][260];
  const int tid = threadIdx.x, lane = tid & 63, wv = tid >> 6;
  const int ot = blockIdx.x >> 5;   // 0..31
  const int ks = blockIdx.x & 31;   // 0..31
  const int kc = ks * 1024;
  const int kg = lane & 7, bg = lane >> 3;
  const int obase = ot * 32 + wv * 8;

  float acc[8][4];
  #pragma unroll
  for (int oi = 0; oi < 8; ++oi)
    #pragma unroll
    for (int j = 0; j < 4; ++j) acc[oi][j] = 0.f;

  for (int st = 0; st < 4; ++st) {
    #pragma unroll
    for (int j = 0; j < 8; ++j) {
      int idx = j * 256 + tid;
      int r = idx >> 6, c = idx & 63;
      *(f32x4*)&Ft[r][c * 4] = *(const f32x4*)(fea2 + (size_t)r * 32768 + kc + st * 256 + c * 4);
    }
    __syncthreads();
    #pragma unroll
    for (int it = 0; it < 8; ++it) {
      const int kof = st * 256 + it * 32 + kg * 4;  // within K-chunk
      f32x4 wreg[8];
      #pragma unroll
      for (int oi = 0; oi < 8; ++oi)
        wreg[oi] = *(const f32x4*)(Wf + (size_t)(obase + oi) * 32768 + kc + kof);
      f32x4 fb[4];
      #pragma unroll
      for (int j = 0; j < 4; ++j)
        fb[j] = *(const f32x4*)&Ft[bg * 4 + j][it * 32 + kg * 4];
      #pragma unroll
      for (int oi = 0; oi < 8; ++oi)
        #pragma unroll
        for (int j = 0; j < 4; ++j)
          #pragma unroll
          for (int c = 0; c < 4; ++c) acc[oi][j] += wreg[oi][c] * fb[j][c];
    }
    __syncthreads();
  }

  #pragma unroll
  for (int oi = 0; oi < 8; ++oi)
    #pragma unroll
    for (int j = 0; j < 4; ++j) {
      float v = acc[oi][j];
      v += __shfl_xor(v, 1); v += __shfl_xor(v, 2); v += __shfl_xor(v, 4);
      acc[oi][j] = v;
    }
  if (kg == 0) {
    #pragma unroll
    for (int j = 0; j < 4; ++j) {
      int b = bg * 4 + j;
      #pragma unroll
      for (int oi = 0; oi < 8; ++oi)
        atomicAdd(&x1[b * 1024 + obase + oi], acc[oi][j]);
    }
  }
}

// grid 256 = 128 o-tiles x 2 k-splits; same decomposition, K=1024
__global__ __launch_bounds__(256, 4) void dim_gemm_kernel(const float* __restrict__ x1,
                                                          const float* __restrict__ Wd,
                                                          float* __restrict__ out) {
  __shared__ __align__(16) float Ft[32][260];
  const int tid = threadIdx.x, lane = tid & 63, wv = tid >> 6;
  const int ot = blockIdx.x >> 1;   // 0..127
  const int ks = blockIdx.x & 1;
  const int kc = ks * 512;
  const int kg = lane & 7, bg = lane >> 3;
  const int obase = ot * 32 + wv * 8;

  float acc[8][4];
  #pragma unroll
  for (int oi = 0; oi < 8; ++oi)
    #pragma unroll
    for (int j = 0; j < 4; ++j) acc[oi][j] = 0.f;

  for (int st = 0; st < 2; ++st) {
    #pragma unroll
    for (int j = 0; j < 8; ++j) {
      int idx = j * 256 + tid;
      int r = idx >> 6, c = idx & 63;
      *(f32x4*)&Ft[r][c * 4] = *(const f32x4*)(x1 + (size_t)r * 1024 + kc + st * 256 + c * 4);
    }
    __syncthreads();
    #pragma unroll
    for (int it = 0; it < 8; ++it) {
      const int kof = st * 256 + it * 32 + kg * 4;
      f32x4 wreg[8];
      #pragma unroll
      for (int oi = 0; oi < 8; ++oi)
        wreg[oi] = *(const f32x4*)(Wd + (size_t)(obase + oi) * 1024 + kc + kof);
      f32x4 fb[4];
      #pragma unroll
      for (int j = 0; j < 4; ++j)
        fb[j] = *(const f32x4*)&Ft[bg * 4 + j][it * 32 + kg * 4];
      #pragma unroll
      for (int oi = 0; oi < 8; ++oi)
        #pragma unroll
        for (int j = 0; j < 4; ++j)
          #pragma unroll
          for (int c = 0; c < 4; ++c) acc[oi][j] += wreg[oi][c] * fb[j][c];
    }
    __syncthreads();
  }

  #pragma unroll
  for (int oi = 0; oi < 8; ++oi)
    #pragma unroll
    for (int j = 0; j < 4; ++j) {
      float v = acc[oi][j];
      v += __shfl_xor(v, 1); v += __shfl_xor(v, 2); v += __shfl_xor(v, 4);
      acc[oi][j] = v;
    }
  if (kg == 0) {
    #pragma unroll
    for (int j = 0; j < 4; ++j) {
      int b = bg * 4 + j;
      #pragma unroll
      for (int oi = 0; oi < 8; ++oi)
        atomicAdd(&out[(size_t)b * 4096 + obase + oi], acc[oi][j]);
    }
  }
}

// ---------------------------------------------------------------------------
extern "C" void kernel_launch(void* const* d_in, const int* in_sizes, int n_in,
                              void* d_out, int out_size, void* d_ws, size_t ws_size,
                              hipStream_t stream) {
  const float* fmap  = (const float*)d_in[0];
  const float* pts   = (const float*)d_in[1];
  const float* Wdiff = (const float*)d_in[2];
  const float* bdiff = (const float*)d_in[3];
  const float* Wagg  = (const float*)d_in[4];
  const float* bagg  = (const float*)d_in[5];
  const float* lng   = (const float*)d_in[6];
  const float* lnb   = (const float*)d_in[7];
  const float* Wflat = (const float*)d_in[8];
  const float* bflat = (const float*)d_in[9];
  const float* Wdim  = (const float*)d_in[10];
  const float* bdim  = (const float*)d_in[11];
  float* out = (float*)d_out;

  char* w = (char*)d_ws;
  size_t off = 0;
  auto alloc = [&](size_t n) { char* p = w + off; off += (n + 255) & ~(size_t)255; return p; };

  float* Z1    = (float*)alloc(16384ull * 1024 * 4);  // 67.1 MB (stage0/1 reuse)
  float* Z2g   = (float*)alloc(4096ull * 1024 * 4);   // 16.8 MB
  u16* Xbf0  = (u16*)alloc(16384ull * KP * 2);
  u16* X1bf  = (u16*)alloc(4096ull * KP * 2);
  u16* Xg    = (u16*)alloc(4096ull * KP * 2);
  u16* WdT   = (u16*)alloc((size_t)NP0 * KP * 2);
  u16* Wa1   = (u16*)alloc(1024ull * KP * 2);
  u16* Wa2   = (u16*)alloc(1024ull * KP * 2);
  u16* Wcomb = (u16*)alloc(1024ull * KP * 2);
  float* czero = (float*)alloc(1024 * 4);
  int* fi0   = (int*)alloc(32 * 128 * 4);
  int* fi1   = (int*)alloc(32 * 32 * 4);
  int* idx0  = (int*)alloc(32 * 128 * 24 * 4);
  int* idx1  = (int*)alloc(32 * 32 * 24 * 4);
  float* npts0 = (float*)alloc(32 * 128 * 2 * 4);
  float* npts1 = (float*)alloc(32 * 32 * 2 * 4);
  float* fea2  = (float*)alloc(32ull * 32 * 1024 * 4);
  float* x1    = (float*)alloc(32 * 1024 * 4);

  // ---- stage-0 inputs (fused bilinear, no transpose round-trip)
  bilinear_fused_kernel<<<dim3(32, 32), 256, 0, stream>>>(fmap, pts, Xbf0);

  // ---- stage 0 (Np=512, S=128)
  fps_kernel<8><<<32, 64, 0, stream>>>(pts, fi0, 512, 128);
  gather_fi_kernel<<<4096, 128, 0, stream>>>(Xbf0, pts, fi0, Xg, npts0, 512, 128);
  knn_kernel<8><<<1024, 256, 0, stream>>>(npts0, pts, idx0, 512, 128);
  wd_transpose_kernel<<<dim3(33, 36), 256, 0, stream>>>(Wdiff, WdT);
  wagg_convert_kernel<<<1024, 256, 0, stream>>>(Wagg, Wa1, Wa2);
  czero_kernel<<<256, 256, 0, stream>>>(bdiff, Wagg, bagg, czero);
  gemm_bt_kernel<1><<<dim3(9, 8), 256, 0, stream>>>(Wa1, WdT, Wcomb, 1024, NP0, KP, KP, KP);
  gemm_bt_kernel<0><<<dim3(8, 128), 256, 0, stream>>>(Xbf0, Wcomb, Z1, 16384, 1024, KP, 1024, 1024);
  gemm_bt_kernel<0><<<dim3(8, 32), 256, 0, stream>>>(Xg, Wa2, Z2g, 4096, 1024, KP, 1024, 1024);
  h_epilogue_kernel<1><<<4096, 256, 0, stream>>>(Z1, Z2g, czero, idx0, fi0, lng, lnb, npts0,
                                                 X1bf, 512, 128);

  // ---- stage 1 (Np=128, S=32)
  fps_kernel<2><<<32, 64, 0, stream>>>(npts0, fi1, 128, 32);
  gather_fi_kernel<<<1024, 128, 0, stream>>>(X1bf, npts0, fi1, Xg, npts1, 128, 32);
  knn_kernel<2><<<256, 256, 0, stream>>>(npts1, npts0, idx1, 128, 32);
  wd_transpose_kernel<<<dim3(33, 36), 256, 0, stream>>>(Wdiff + 1026 * 1026, WdT);
  wagg_convert_kernel<<<1024, 256, 0, stream>>>(Wagg + 1024 * 2052, Wa1, Wa2);
  czero_kernel<<<256, 256, 0, stream>>>(bdiff + 1026, Wagg + 1024 * 2052, bagg + 1024, czero);
  gemm_bt_kernel<1><<<dim3(9, 8), 256, 0, stream>>>(Wa1, WdT, Wcomb, 1024, NP0, KP, KP, KP);
  gemm_bt_kernel<0><<<dim3(8, 32), 256, 0, stream>>>(X1bf, Wcomb, Z1, 4096, 1024, KP, 1024, 1024);
  gemm_bt_kernel<0><<<dim3(8, 8), 256, 0, stream>>>(Xg, Wa2, Z2g, 1024, 1024, KP, 1024, 1024);
  h_epilogue_kernel<0><<<1024, 256, 0, stream>>>(Z1, Z2g, czero, idx1, fi1, lng + 1024, lnb + 1024,
                                                 npts1, fea2, 128, 32);

  // ---- final MLP
  x1_init_kernel<<<128, 256, 0, stream>>>(bflat, x1);
  flat_gemm_kernel<<<1024, 256, 0, stream>>>(fea2, Wflat, x1);
  out_init_kernel<<<512, 256, 0, stream>>>(bdim, out);
  dim_gemm_kernel<<<256, 256, 0, stream>>>(x1, Wdim, out);
}

// Round 4
// 969.664 us; speedup vs baseline: 1.4623x; 1.0413x over previous
//
#include <hip/hip_runtime.h>

// ---------------------------------------------------------------------------
// GeoRegionSampler: restructured pipeline
//   X = [bilinear_fea | pts] (bf16, padded 1026->1056); bilinear fused with
//   fmap channel-tile staging in LDS (no transpose round-trip).
//   Wcomb = Wa1 @ Wd   (bf16 MFMA GEMM)
//   Z1 = X @ Wcomb^T ; Z2 = X[fi] @ Wa2^T ; czero = b_diff@Wa1^T + b_agg
//   h[b,s,k] = relu(Z1[idx]-Z1[fi]+Z2[s]+czero) -> LN -> mean_k  (fused)
//   final fp32 GEMMs: BOTH W and F staged in LDS with 1KB/wave-instr
//   coalesced loads (R3's 128B-granular W broadcast loads ran DRAM at 9%
//   efficiency -> 732 GB/s; this is the fix). acc[8o][4b]=32 VGPR.
// FPS/kNN: fp32 bit-exact (fp contract off), first-index tie-break.
// ---------------------------------------------------------------------------

typedef float f32x4 __attribute__((ext_vector_type(4)));
typedef short bf16x8 __attribute__((ext_vector_type(8)));
typedef unsigned short u16;
typedef u16 u16x4 __attribute__((ext_vector_type(4)));
typedef unsigned int u32;
typedef u32 u32x4 __attribute__((ext_vector_type(4)));

typedef const void __attribute__((address_space(1)))* gvp;
typedef void __attribute__((address_space(3)))* svp;

__device__ __forceinline__ u16 f2bf(float f) {
  union { float f; u32 u; } x; x.f = f;
  u32 r = x.u + 0x7fffu + ((x.u >> 16) & 1u);
  return (u16)(r >> 16);
}

#define KP 1056   // padded Dp (1026 -> 33*32)
#define NP0 1152  // padded N for weight-combine GEMM (9*128)

// ------- fused bilinear: stage fmap[b][ct*32..+31][:] in LDS, interp -------
__global__ __launch_bounds__(256, 2) void bilinear_fused_kernel(const float* __restrict__ fmap,
                                                                const float* __restrict__ pts,
                                                                u16* __restrict__ X) {
  __shared__ float fmS[32][580];  // 580: f32x4-aligned, stride%32=4 rotates banks
  const int ct = blockIdx.x, b = blockIdx.y;
  const int t = threadIdx.x;
  const float* src = fmap + ((size_t)b * 1024 + ct * 32) * 576;
  const int tr = t >> 3, ti = t & 7;  // 32 rows x 8 threads/row
  #pragma unroll
  for (int j = 0; j < 18; ++j) {
    int c4 = j * 8 + ti;  // 0..143 f32x4 per row
    *(f32x4*)&fmS[tr][c4 * 4] = *(const f32x4*)(src + (size_t)tr * 576 + c4 * 4);
  }
  __syncthreads();
  #pragma unroll
  for (int pass = 0; pass < 2; ++pass) {
    const int n = pass * 256 + t;
    const int pidx = b * 512 + n;
    float p0 = pts[(size_t)pidx * 2], p1 = pts[(size_t)pidx * 2 + 1];
    float gy = p0 * 23.f, gx = p1 * 23.f;
    float y0f = floorf(gy), x0f = floorf(gx);
    float wy = gy - y0f, wx = gx - x0f;
    int y0 = (int)y0f; y0 = y0 < 0 ? 0 : (y0 > 23 ? 23 : y0);
    int x0 = (int)x0f; x0 = x0 < 0 ? 0 : (x0 > 23 ? 23 : x0);
    int y1 = y0 + 1 > 23 ? 23 : y0 + 1;
    int x1 = x0 + 1 > 23 ? 23 : x0 + 1;
    float w00 = (1.f - wy) * (1.f - wx), w01 = (1.f - wy) * wx;
    float w10 = wy * (1.f - wx), w11 = wy * wx;
    const int i00 = y0 * 24 + x0, i01 = y0 * 24 + x1;
    const int i10 = y1 * 24 + x0, i11 = y1 * 24 + x1;
    size_t ro = (size_t)pidx * KP + ct * 32;
    #pragma unroll
    for (int cq = 0; cq < 8; ++cq) {
      u16x4 o4;
      #pragma unroll
      for (int cc = 0; cc < 4; ++cc) {
        int c = cq * 4 + cc;
        float v = w00 * fmS[c][i00] + w01 * fmS[c][i01] +
                  w10 * fmS[c][i10] + w11 * fmS[c][i11];
        o4[cc] = f2bf(v);
      }
      *(u16x4*)(X + ro + cq * 4) = o4;
    }
    if (ct == 31) {
      size_t rb = (size_t)pidx * KP;
      X[rb + 1024] = f2bf(p0);
      X[rb + 1025] = f2bf(p1);
      #pragma unroll
      for (int z = 0; z < 15; ++z) ((u32*)(X + rb + 1026))[z] = 0;
    }
  }
}

// ---------------- FPS: one wave per batch, bit-exact ------------------------
template <int PPL>
__global__ void fps_kernel(const float* __restrict__ pts, int* __restrict__ fi,
                           int Np, int S) {
  #pragma clang fp contract(off)
  int b = blockIdx.x;
  int lane = threadIdx.x;
  float px[PPL], py[PPL], dist[PPL];
  #pragma unroll
  for (int j = 0; j < PPL; ++j) {
    int n = j * 64 + lane;
    px[j] = pts[((size_t)b * Np + n) * 2];
    py[j] = pts[((size_t)b * Np + n) * 2 + 1];
    dist[j] = 1e10f;
  }
  int far = 0;
  for (int s = 0; s < S; ++s) {
    if (lane == 0) fi[b * S + s] = far;
    float cx = pts[((size_t)b * Np + far) * 2];
    float cy = pts[((size_t)b * Np + far) * 2 + 1];
    float bv = -1.f; int bi = 0;
    #pragma unroll
    for (int j = 0; j < PPL; ++j) {
      float dx = px[j] - cx, dy = py[j] - cy;
      float d = dx * dx + dy * dy;
      float nd = fminf(dist[j], d);
      dist[j] = nd;
      if (nd > bv) { bv = nd; bi = j * 64 + lane; }
    }
    #pragma unroll
    for (int off = 32; off; off >>= 1) {
      float ov = __shfl_xor(bv, off);
      int oi = __shfl_xor(bi, off);
      if (ov > bv || (ov == bv && oi < bi)) { bv = ov; bi = oi; }
    }
    far = bi;
  }
}

// ---------------- kNN: one wave per (b,s), bit-exact ------------------------
template <int PPL>
__global__ __launch_bounds__(256) void knn_kernel(const float* __restrict__ qpts,
                                                  const float* __restrict__ rpts,
                                                  int* __restrict__ idxK, int Np, int S) {
  #pragma clang fp contract(off)
  int lane = threadIdx.x & 63, wv = threadIdx.x >> 6;
  int q = blockIdx.x * 4 + wv;
  int b = q / S;
  float ax = qpts[(size_t)q * 2], ay = qpts[(size_t)q * 2 + 1];
  float a2 = ax * ax + ay * ay;
  float d2[PPL];
  #pragma unroll
  for (int j = 0; j < PPL; ++j) {
    int n = j * 64 + lane;
    float bx = rpts[((size_t)b * Np + n) * 2];
    float by = rpts[((size_t)b * Np + n) * 2 + 1];
    float b2 = bx * bx + by * by;
    float dot = ax * bx + ay * by;
    float t = a2 + b2;
    float m2 = 2.f * dot;
    d2[j] = t - m2;
  }
  for (int k = 0; k < 24; ++k) {
    float bv = 3.4e38f; int bi = 1 << 30;
    #pragma unroll
    for (int j = 0; j < PPL; ++j)
      if (d2[j] < bv) { bv = d2[j]; bi = j * 64 + lane; }
    #pragma unroll
    for (int off = 32; off; off >>= 1) {
      float ov = __shfl_xor(bv, off);
      int oi = __shfl_xor(bi, off);
      if (ov < bv || (ov == bv && oi < bi)) { bv = ov; bi = oi; }
    }
    if (lane == 0) idxK[(size_t)q * 24 + k] = bi;
    #pragma unroll
    for (int j = 0; j < PPL; ++j)
      if (j * 64 + lane == bi) d2[j] = 3.4e38f;
  }
}

// ---------------- gather X rows at fi; emit new_pts -------------------------
__global__ __launch_bounds__(128) void gather_fi_kernel(const u16* __restrict__ Xsrc,
                                                        const float* __restrict__ pts,
                                                        const int* __restrict__ fi,
                                                        u16* __restrict__ Xg,
                                                        float* __restrict__ npts,
                                                        int Np, int S) {
  int q = blockIdx.x;
  int b = q / S;
  int t = threadIdx.x;
  int r = fi[q];
  const u32x4* src = (const u32x4*)(Xsrc + ((size_t)b * Np + r) * KP);
  u32x4* dst = (u32x4*)(Xg + (size_t)q * KP);
  dst[t] = src[t];
  int t2 = t + 128;
  if (t2 < 132) dst[t2] = src[t2];
  if (t == 0) {
    npts[(size_t)q * 2] = pts[((size_t)b * Np + r) * 2];
    npts[(size_t)q * 2 + 1] = pts[((size_t)b * Np + r) * 2 + 1];
  }
}

// ---------------- weight prep ----------------------------------------------
__global__ __launch_bounds__(256) void wd_transpose_kernel(const float* __restrict__ Wd,
                                                           u16* __restrict__ WdT) {
  __shared__ float tbuf[32][33];
  int tx = threadIdx.x & 31, ty = threadIdx.x >> 5;
  int ot = blockIdx.x * 32, dt = blockIdx.y * 32;
  #pragma unroll
  for (int j = 0; j < 4; ++j) {
    int o = ot + ty + 8 * j, d = dt + tx;
    tbuf[ty + 8 * j][tx] = (o < 1026 && d < 1026) ? Wd[(size_t)o * 1026 + d] : 0.f;
  }
  __syncthreads();
  #pragma unroll
  for (int j = 0; j < 4; ++j) {
    int d = dt + ty + 8 * j, o = ot + tx;
    if (o < KP) WdT[(size_t)d * KP + o] = f2bf(tbuf[tx][ty + 8 * j]);
  }
}

__global__ __launch_bounds__(256) void wagg_convert_kernel(const float* __restrict__ Wagg,
                                                           u16* __restrict__ Wa1,
                                                           u16* __restrict__ Wa2) {
  int c = blockIdx.x, t = threadIdx.x;
  const float* row = Wagg + (size_t)c * 2052;
  for (int d = t; d < KP; d += 256) {
    Wa1[(size_t)c * KP + d] = (d < 1026) ? f2bf(row[d]) : (u16)0;
    Wa2[(size_t)c * KP + d] = (d < 1026) ? f2bf(row[1026 + d]) : (u16)0;
  }
}

__global__ __launch_bounds__(256) void czero_kernel(const float* __restrict__ bdiff,
                                                    const float* __restrict__ Wagg,
                                                    const float* __restrict__ bagg,
                                                    float* __restrict__ czero) {
  int lane = threadIdx.x & 63, wv = threadIdx.x >> 6;
  int c = blockIdx.x * 4 + wv;
  float acc = 0.f;
  for (int o = lane; o < 1026; o += 64) acc += bdiff[o] * Wagg[(size_t)c * 2052 + o];
  #pragma unroll
  for (int off = 32; off; off >>= 1) acc += __shfl_xor(acc, off);
  if (lane == 0) czero[c] = acc + bagg[c];
}

// ---------------- bf16 MFMA GEMM: C[M,N] = A[M,K] @ Bt[N,K]^T ---------------
template <int BF16OUT>
__global__ __launch_bounds__(256) void gemm_bt_kernel(const u16* __restrict__ A,
                                                      const u16* __restrict__ Bt,
                                                      void* __restrict__ Cout,
                                                      int M, int N, int K, int ldc, int nvalid) {
  __shared__ __align__(16) u16 As[128 * 32];
  __shared__ __align__(16) u16 Bs[128 * 32];
  const int tid = threadIdx.x;
  const int lane = tid & 63;
  const int wv = tid >> 6;
  const int m0 = blockIdx.y * 128;
  const int n0 = blockIdx.x * 128;
  const int wm = (wv >> 1) * 64;
  const int wn = (wv & 1) * 64;

  f32x4 acc[4][4];
  #pragma unroll
  for (int i = 0; i < 4; ++i)
    #pragma unroll
    for (int j = 0; j < 4; ++j)
      #pragma unroll
      for (int c = 0; c < 4; ++c) acc[i][j][c] = 0.f;

  const int ch0 = wv * 2;
  const int rin = lane >> 2;        // row within 16-row chunk
  const int cin = (lane & 3) * 8;   // u16 col offset

  for (int k0 = 0; k0 < K; k0 += 32) {
    #pragma unroll
    for (int i = 0; i < 2; ++i) {
      const int ch = ch0 + i;
      const int row = ch * 16 + rin;
      const u16* ga = A + (size_t)(m0 + row) * K + (k0 + cin);
      const u16* gb = Bt + (size_t)(n0 + row) * K + (k0 + cin);
      __builtin_amdgcn_global_load_lds((gvp)ga, (svp)(As + ch * 512), 16, 0, 0);
      __builtin_amdgcn_global_load_lds((gvp)gb, (svp)(Bs + ch * 512), 16, 0, 0);
    }
    __syncthreads();
    const int rf = lane & 15;
    const int qf = (lane >> 4) * 8;
    bf16x8 af[4], bfv[4];
    #pragma unroll
    for (int mi = 0; mi < 4; ++mi)
      af[mi] = *(const bf16x8*)(As + (wm + mi * 16 + rf) * 32 + qf);
    #pragma unroll
    for (int ni = 0; ni < 4; ++ni)
      bfv[ni] = *(const bf16x8*)(Bs + (wn + ni * 16 + rf) * 32 + qf);
    #pragma unroll
    for (int mi = 0; mi < 4; ++mi)
      #pragma unroll
      for (int ni = 0; ni < 4; ++ni)
        acc[mi][ni] = __builtin_amdgcn_mfma_f32_16x16x32_bf16(af[mi], bfv[ni], acc[mi][ni], 0, 0, 0);
    __syncthreads();
  }

  const int rq = (lane >> 4) * 4;
  const int cf = lane & 15;
  #pragma unroll
  for (int mi = 0; mi < 4; ++mi) {
    #pragma unroll
    for (int ni = 0; ni < 4; ++ni) {
      const int col = n0 + wn + ni * 16 + cf;
      #pragma unroll
      for (int r = 0; r < 4; ++r) {
        const int row = m0 + wm + mi * 16 + rq + r;
        const float v = acc[mi][ni][r];
        if (BF16OUT) {
          if (col < nvalid) ((u16*)Cout)[(size_t)row * ldc + col] = f2bf(v);
        } else {
          ((float*)Cout)[(size_t)row * ldc + col] = v;
        }
      }
    }
  }
}

// ---------------- fused gather + relu + LN + mean_k -------------------------
template <int BF16OUT>
__global__ __launch_bounds__(256) void h_epilogue_kernel(const float* __restrict__ Z1,
                                                         const float* __restrict__ Z2g,
                                                         const float* __restrict__ czero,
                                                         const int* __restrict__ idxK,
                                                         const int* __restrict__ fi,
                                                         const float* __restrict__ g,
                                                         const float* __restrict__ bb,
                                                         const float* __restrict__ npts,
                                                         void* __restrict__ outp,
                                                         int Np, int S) {
  __shared__ float r1[4];
  __shared__ float r2[4];
  int q = blockIdx.x;
  int b = q / S;
  int t = threadIdx.x;
  int lane = t & 63, wv = t >> 6;
  int fiv = fi[q];
  const f32x4* z2 = (const f32x4*)(Z2g + (size_t)q * 1024);
  const f32x4* zf = (const f32x4*)(Z1 + ((size_t)b * Np + fiv) * 1024);
  const f32x4* cz = (const f32x4*)czero;
  f32x4 base = z2[t] + cz[t] - zf[t];
  f32x4 gv = ((const f32x4*)g)[t];
  f32x4 bv = ((const f32x4*)bb)[t];
  f32x4 acc;
  #pragma unroll
  for (int c = 0; c < 4; ++c) acc[c] = 0.f;
  for (int k = 0; k < 24; ++k) {
    int n = idxK[(size_t)q * 24 + k];
    const f32x4* zr = (const f32x4*)(Z1 + ((size_t)b * Np + n) * 1024);
    f32x4 v = zr[t] + base;
    #pragma unroll
    for (int c = 0; c < 4; ++c) v[c] = fmaxf(v[c], 0.f);
    float s1 = v[0] + v[1] + v[2] + v[3];
    float s2 = v[0] * v[0] + v[1] * v[1] + v[2] * v[2] + v[3] * v[3];
    #pragma unroll
    for (int off = 32; off; off >>= 1) {
      s1 += __shfl_xor(s1, off);
      s2 += __shfl_xor(s2, off);
    }
    if (lane == 0) { r1[wv] = s1; r2[wv] = s2; }
    __syncthreads();
    s1 = r1[0] + r1[1] + r1[2] + r1[3];
    s2 = r2[0] + r2[1] + r2[2] + r2[3];
    __syncthreads();
    float m = s1 * (1.f / 1024.f);
    float var = s2 * (1.f / 1024.f) - m * m;
    float rs = rsqrtf(var + 1e-5f);
    #pragma unroll
    for (int c = 0; c < 4; ++c) acc[c] += (v[c] - m) * rs * gv[c] + bv[c];
  }
  #pragma unroll
  for (int c = 0; c < 4; ++c) acc[c] *= (1.f / 24.f);
  if (BF16OUT) {
    u16* X = (u16*)outp;
    size_t ro = (size_t)q * KP;
    u16x4 o4;
    #pragma unroll
    for (int c = 0; c < 4; ++c) o4[c] = f2bf(acc[c]);
    *(u16x4*)(X + ro + t * 4) = o4;
    if (t == 0) {
      X[ro + 1024] = f2bf(npts[(size_t)q * 2]);
      X[ro + 1025] = f2bf(npts[(size_t)q * 2 + 1]);
    }
    if (t < 15) ((u32*)(X + ro + 1026))[t] = 0;
  } else {
    ((f32x4*)outp)[(size_t)q * 256 + t] = acc;
  }
}

// ---------------- final fp32 GEMMs v4: W and F both LDS-staged --------------
// out[b, obase+oi] (+)= sum_k F[b, kc+k] * W[obase+oi, kc+k]
// Staging: wave loads one 1KB row-chunk per instr (r=j*4+wv, col=lane*4).
// Compute: lane=(bg=lane>>3, kg=lane&7); acc[8o][4b]=32 VGPR, no spill.
__global__ __launch_bounds__(256) void x1_init_kernel(const float* __restrict__ bflat,
                                                      float* __restrict__ x1) {
  int i = blockIdx.x * 256 + threadIdx.x;  // 32768
  x1[i] = bflat[i & 1023];
}

__global__ __launch_bounds__(256) void out_init_kernel(const float* __restrict__ bdim,
                                                       float* __restrict__ out) {
  int i = blockIdx.x * 256 + threadIdx.x;  // 131072
  out[i] = bdim[i & 4095];
}

__global__ __launch_bounds__(256, 2) void mlp_gemm_kernel(const float* __restrict__ F,
                                                          const float* __restrict__ W,
                                                          float* __restrict__ outp,
                                                          int ks_bits, int nst,
                                                          int kstride, int ostride) {
  __shared__ __align__(16) float Ws[32][260];
  __shared__ __align__(16) float Ft[32][260];
  const int tid = threadIdx.x, lane = tid & 63, wv = tid >> 6;
  const int ot = blockIdx.x >> ks_bits;
  const int ks = blockIdx.x & ((1 << ks_bits) - 1);
  const int kc = ks * nst * 256;
  const int kg = lane & 7, bg = lane >> 3;
  const int obase = ot * 32 + wv * 8;

  float acc[8][4];
  #pragma unroll
  for (int oi = 0; oi < 8; ++oi)
    #pragma unroll
    for (int j = 0; j < 4; ++j) acc[oi][j] = 0.f;

  for (int st = 0; st < nst; ++st) {
    const int kb = kc + st * 256;
    __syncthreads();
    #pragma unroll
    for (int j = 0; j < 8; ++j) {
      const int r = j * 4 + wv;
      *(f32x4*)&Ws[r][lane * 4] =
          *(const f32x4*)(W + (size_t)(ot * 32 + r) * kstride + kb + lane * 4);
      *(f32x4*)&Ft[r][lane * 4] =
          *(const f32x4*)(F + (size_t)r * kstride + kb + lane * 4);
    }
    __syncthreads();
    #pragma unroll
    for (int it = 0; it < 8; ++it) {
      const int co = it * 32 + kg * 4;
      f32x4 wreg[8];
      #pragma unroll
      for (int oi = 0; oi < 8; ++oi) wreg[oi] = *(const f32x4*)&Ws[wv * 8 + oi][co];
      f32x4 fb[4];
      #pragma unroll
      for (int j = 0; j < 4; ++j) fb[j] = *(const f32x4*)&Ft[bg * 4 + j][co];
      #pragma unroll
      for (int oi = 0; oi < 8; ++oi)
        #pragma unroll
        for (int j = 0; j < 4; ++j)
          #pragma unroll
          for (int c = 0; c < 4; ++c) acc[oi][j] += wreg[oi][c] * fb[j][c];
    }
  }

  #pragma unroll
  for (int oi = 0; oi < 8; ++oi)
    #pragma unroll
    for (int j = 0; j < 4; ++j) {
      float v = acc[oi][j];
      v += __shfl_xor(v, 1); v += __shfl_xor(v, 2); v += __shfl_xor(v, 4);
      acc[oi][j] = v;
    }
  if (kg == 0) {
    #pragma unroll
    for (int j = 0; j < 4; ++j) {
      int b = bg * 4 + j;
      #pragma unroll
      for (int oi = 0; oi < 8; ++oi)
        atomicAdd(&outp[(size_t)b * ostride + obase + oi], acc[oi][j]);
    }
  }
}

// ---------------------------------------------------------------------------
extern "C" void kernel_launch(void* const* d_in, const int* in_sizes, int n_in,
                              void* d_out, int out_size, void* d_ws, size_t ws_size,
                              hipStream_t stream) {
  const float* fmap  = (const float*)d_in[0];
  const float* pts   = (const float*)d_in[1];
  const float* Wdiff = (const float*)d_in[2];
  const float* bdiff = (const float*)d_in[3];
  const float* Wagg  = (const float*)d_in[4];
  const float* bagg  = (const float*)d_in[5];
  const float* lng   = (const float*)d_in[6];
  const float* lnb   = (const float*)d_in[7];
  const float* Wflat = (const float*)d_in[8];
  const float* bflat = (const float*)d_in[9];
  const float* Wdim  = (const float*)d_in[10];
  const float* bdim  = (const float*)d_in[11];
  float* out = (float*)d_out;

  char* w = (char*)d_ws;
  size_t off = 0;
  auto alloc = [&](size_t n) { char* p = w + off; off += (n + 255) & ~(size_t)255; return p; };

  float* Z1    = (float*)alloc(16384ull * 1024 * 4);  // 67.1 MB (stage0/1 reuse)
  float* Z2g   = (float*)alloc(4096ull * 1024 * 4);   // 16.8 MB
  u16* Xbf0  = (u16*)alloc(16384ull * KP * 2);
  u16* X1bf  = (u16*)alloc(4096ull * KP * 2);
  u16* Xg    = (u16*)alloc(4096ull * KP * 2);
  u16* WdT   = (u16*)alloc((size_t)NP0 * KP * 2);
  u16* Wa1   = (u16*)alloc(1024ull * KP * 2);
  u16* Wa2   = (u16*)alloc(1024ull * KP * 2);
  u16* Wcomb = (u16*)alloc(1024ull * KP * 2);
  float* czero = (float*)alloc(1024 * 4);
  int* fi0   = (int*)alloc(32 * 128 * 4);
  int* fi1   = (int*)alloc(32 * 32 * 4);
  int* idx0  = (int*)alloc(32 * 128 * 24 * 4);
  int* idx1  = (int*)alloc(32 * 32 * 24 * 4);
  float* npts0 = (float*)alloc(32 * 128 * 2 * 4);
  float* npts1 = (float*)alloc(32 * 32 * 2 * 4);
  float* fea2  = (float*)alloc(32ull * 32 * 1024 * 4);
  float* x1    = (float*)alloc(32 * 1024 * 4);

  // ---- stage-0 inputs (fused bilinear, no transpose round-trip)
  bilinear_fused_kernel<<<dim3(32, 32), 256, 0, stream>>>(fmap, pts, Xbf0);

  // ---- stage 0 (Np=512, S=128)
  fps_kernel<8><<<32, 64, 0, stream>>>(pts, fi0, 512, 128);
  gather_fi_kernel<<<4096, 128, 0, stream>>>(Xbf0, pts, fi0, Xg, npts0, 512, 128);
  knn_kernel<8><<<1024, 256, 0, stream>>>(npts0, pts, idx0, 512, 128);
  wd_transpose_kernel<<<dim3(33, 36), 256, 0, stream>>>(Wdiff, WdT);
  wagg_convert_kernel<<<1024, 256, 0, stream>>>(Wagg, Wa1, Wa2);
  czero_kernel<<<256, 256, 0, stream>>>(bdiff, Wagg, bagg, czero);
  gemm_bt_kernel<1><<<dim3(9, 8), 256, 0, stream>>>(Wa1, WdT, Wcomb, 1024, NP0, KP, KP, KP);
  gemm_bt_kernel<0><<<dim3(8, 128), 256, 0, stream>>>(Xbf0, Wcomb, Z1, 16384, 1024, KP, 1024, 1024);
  gemm_bt_kernel<0><<<dim3(8, 32), 256, 0, stream>>>(Xg, Wa2, Z2g, 4096, 1024, KP, 1024, 1024);
  h_epilogue_kernel<1><<<4096, 256, 0, stream>>>(Z1, Z2g, czero, idx0, fi0, lng, lnb, npts0,
                                                 X1bf, 512, 128);

  // ---- stage 1 (Np=128, S=32)
  fps_kernel<2><<<32, 64, 0, stream>>>(npts0, fi1, 128, 32);
  gather_fi_kernel<<<1024, 128, 0, stream>>>(X1bf, npts0, fi1, Xg, npts1, 128, 32);
  knn_kernel<2><<<256, 256, 0, stream>>>(npts1, npts0, idx1, 128, 32);
  wd_transpose_kernel<<<dim3(33, 36), 256, 0, stream>>>(Wdiff + 1026 * 1026, WdT);
  wagg_convert_kernel<<<1024, 256, 0, stream>>>(Wagg + 1024 * 2052, Wa1, Wa2);
  czero_kernel<<<256, 256, 0, stream>>>(bdiff + 1026, Wagg + 1024 * 2052, bagg + 1024, czero);
  gemm_bt_kernel<1><<<dim3(9, 8), 256, 0, stream>>>(Wa1, WdT, Wcomb, 1024, NP0, KP, KP, KP);
  gemm_bt_kernel<0><<<dim3(8, 32), 256, 0, stream>>>(X1bf, Wcomb, Z1, 4096, 1024, KP, 1024, 1024);
  gemm_bt_kernel<0><<<dim3(8, 8), 256, 0, stream>>>(Xg, Wa2, Z2g, 1024, 1024, KP, 1024, 1024);
  h_epilogue_kernel<0><<<1024, 256, 0, stream>>>(Z1, Z2g, czero, idx1, fi1, lng + 1024, lnb + 1024,
                                                 npts1, fea2, 128, 32);

  // ---- final MLP
  x1_init_kernel<<<128, 256, 0, stream>>>(bflat, x1);
  mlp_gemm_kernel<<<1024, 256, 0, stream>>>(fea2, Wflat, x1, 5, 4, 32768, 1024);
  out_init_kernel<<<512, 256, 0, stream>>>(bdim, out);
  mlp_gemm_kernel<<<256, 256, 0, stream>>>(x1, Wdim, out, 1, 2, 1024, 4096);
}

// Round 5
// 811.349 us; speedup vs baseline: 1.7476x; 1.1951x over previous
//
#include <hip/hip_runtime.h>

// ---------------------------------------------------------------------------
// GeoRegionSampler: restructured pipeline
//   X = [bilinear_fea | pts] (bf16, padded 1026->1056); bilinear fused with
//   fmap channel-tile staging in LDS.
//   Wcomb = Wa1 @ Wd   (bf16 MFMA GEMM)
//   Z1 = X @ Wcomb^T ; Z2 = X[fi] @ Wa2^T ; czero = b_diff@Wa1^T + b_agg
//   h[b,s,k] = relu(Z1[idx]-Z1[fi]+Z2[s]+czero) -> LN -> mean_k  (fused;
//   emits fea2 as bf16)
//   final MLP: MFMA GEMMs streaming W as fp32 via global_load_lds (XOR-
//   swizzled LDS) with in-register fp32->bf16 convert; K-split partials +
//   reduce kernels. (R3/R4's phase-barriered VALU GEMM sat at 660 GB/s --
//   insufficient memory-level parallelism, not granularity; this replaces
//   the structure with the proven continuously-streaming m97 K-loop.)
// FPS/kNN: fp32 bit-exact (fp contract off), first-index tie-break.
// ---------------------------------------------------------------------------

typedef float f32x4 __attribute__((ext_vector_type(4)));
typedef short bf16x8 __attribute__((ext_vector_type(8)));
typedef unsigned short u16;
typedef u16 u16x4 __attribute__((ext_vector_type(4)));
typedef unsigned int u32;
typedef u32 u32x4 __attribute__((ext_vector_type(4)));

typedef const void __attribute__((address_space(1)))* gvp;
typedef void __attribute__((address_space(3)))* svp;

__device__ __forceinline__ u16 f2bf(float f) {
  union { float f; u32 u; } x; x.f = f;
  u32 r = x.u + 0x7fffu + ((x.u >> 16) & 1u);
  return (u16)(r >> 16);
}

#define KP 1056   // padded Dp (1026 -> 33*32)
#define NP0 1152  // padded N for weight-combine GEMM (9*128)

// ------- fused bilinear: stage fmap[b][ct*32..+31][:] in LDS, interp -------
__global__ __launch_bounds__(256, 2) void bilinear_fused_kernel(const float* __restrict__ fmap,
                                                                const float* __restrict__ pts,
                                                                u16* __restrict__ X) {
  __shared__ float fmS[32][580];
  const int ct = blockIdx.x, b = blockIdx.y;
  const int t = threadIdx.x;
  const float* src = fmap + ((size_t)b * 1024 + ct * 32) * 576;
  const int tr = t >> 3, ti = t & 7;
  #pragma unroll
  for (int j = 0; j < 18; ++j) {
    int c4 = j * 8 + ti;
    *(f32x4*)&fmS[tr][c4 * 4] = *(const f32x4*)(src + (size_t)tr * 576 + c4 * 4);
  }
  __syncthreads();
  #pragma unroll
  for (int pass = 0; pass < 2; ++pass) {
    const int n = pass * 256 + t;
    const int pidx = b * 512 + n;
    float p0 = pts[(size_t)pidx * 2], p1 = pts[(size_t)pidx * 2 + 1];
    float gy = p0 * 23.f, gx = p1 * 23.f;
    float y0f = floorf(gy), x0f = floorf(gx);
    float wy = gy - y0f, wx = gx - x0f;
    int y0 = (int)y0f; y0 = y0 < 0 ? 0 : (y0 > 23 ? 23 : y0);
    int x0 = (int)x0f; x0 = x0 < 0 ? 0 : (x0 > 23 ? 23 : x0);
    int y1 = y0 + 1 > 23 ? 23 : y0 + 1;
    int x1 = x0 + 1 > 23 ? 23 : x0 + 1;
    float w00 = (1.f - wy) * (1.f - wx), w01 = (1.f - wy) * wx;
    float w10 = wy * (1.f - wx), w11 = wy * wx;
    const int i00 = y0 * 24 + x0, i01 = y0 * 24 + x1;
    const int i10 = y1 * 24 + x0, i11 = y1 * 24 + x1;
    size_t ro = (size_t)pidx * KP + ct * 32;
    #pragma unroll
    for (int cq = 0; cq < 8; ++cq) {
      u16x4 o4;
      #pragma unroll
      for (int cc = 0; cc < 4; ++cc) {
        int c = cq * 4 + cc;
        float v = w00 * fmS[c][i00] + w01 * fmS[c][i01] +
                  w10 * fmS[c][i10] + w11 * fmS[c][i11];
        o4[cc] = f2bf(v);
      }
      *(u16x4*)(X + ro + cq * 4) = o4;
    }
    if (ct == 31) {
      size_t rb = (size_t)pidx * KP;
      X[rb + 1024] = f2bf(p0);
      X[rb + 1025] = f2bf(p1);
      #pragma unroll
      for (int z = 0; z < 15; ++z) ((u32*)(X + rb + 1026))[z] = 0;
    }
  }
}

// ---------------- FPS: one wave per batch, bit-exact ------------------------
template <int PPL>
__global__ void fps_kernel(const float* __restrict__ pts, int* __restrict__ fi,
                           int Np, int S) {
  #pragma clang fp contract(off)
  int b = blockIdx.x;
  int lane = threadIdx.x;
  float px[PPL], py[PPL], dist[PPL];
  #pragma unroll
  for (int j = 0; j < PPL; ++j) {
    int n = j * 64 + lane;
    px[j] = pts[((size_t)b * Np + n) * 2];
    py[j] = pts[((size_t)b * Np + n) * 2 + 1];
    dist[j] = 1e10f;
  }
  int far = 0;
  for (int s = 0; s < S; ++s) {
    if (lane == 0) fi[b * S + s] = far;
    float cx = pts[((size_t)b * Np + far) * 2];
    float cy = pts[((size_t)b * Np + far) * 2 + 1];
    float bv = -1.f; int bi = 0;
    #pragma unroll
    for (int j = 0; j < PPL; ++j) {
      float dx = px[j] - cx, dy = py[j] - cy;
      float d = dx * dx + dy * dy;
      float nd = fminf(dist[j], d);
      dist[j] = nd;
      if (nd > bv) { bv = nd; bi = j * 64 + lane; }
    }
    #pragma unroll
    for (int off = 32; off; off >>= 1) {
      float ov = __shfl_xor(bv, off);
      int oi = __shfl_xor(bi, off);
      if (ov > bv || (ov == bv && oi < bi)) { bv = ov; bi = oi; }
    }
    far = bi;
  }
}

// ---------------- kNN: one wave per (b,s), bit-exact ------------------------
template <int PPL>
__global__ __launch_bounds__(256) void knn_kernel(const float* __restrict__ qpts,
                                                  const float* __restrict__ rpts,
                                                  int* __restrict__ idxK, int Np, int S) {
  #pragma clang fp contract(off)
  int lane = threadIdx.x & 63, wv = threadIdx.x >> 6;
  int q = blockIdx.x * 4 + wv;
  int b = q / S;
  float ax = qpts[(size_t)q * 2], ay = qpts[(size_t)q * 2 + 1];
  float a2 = ax * ax + ay * ay;
  float d2[PPL];
  #pragma unroll
  for (int j = 0; j < PPL; ++j) {
    int n = j * 64 + lane;
    float bx = rpts[((size_t)b * Np + n) * 2];
    float by = rpts[((size_t)b * Np + n) * 2 + 1];
    float b2 = bx * bx + by * by;
    float dot = ax * bx + ay * by;
    float t = a2 + b2;
    float m2 = 2.f * dot;
    d2[j] = t - m2;
  }
  for (int k = 0; k < 24; ++k) {
    float bv = 3.4e38f; int bi = 1 << 30;
    #pragma unroll
    for (int j = 0; j < PPL; ++j)
      if (d2[j] < bv) { bv = d2[j]; bi = j * 64 + lane; }
    #pragma unroll
    for (int off = 32; off; off >>= 1) {
      float ov = __shfl_xor(bv, off);
      int oi = __shfl_xor(bi, off);
      if (ov < bv || (ov == bv && oi < bi)) { bv = ov; bi = oi; }
    }
    if (lane == 0) idxK[(size_t)q * 24 + k] = bi;
    #pragma unroll
    for (int j = 0; j < PPL; ++j)
      if (j * 64 + lane == bi) d2[j] = 3.4e38f;
  }
}

// ---------------- gather X rows at fi; emit new_pts -------------------------
__global__ __launch_bounds__(128) void gather_fi_kernel(const u16* __restrict__ Xsrc,
                                                        const float* __restrict__ pts,
                                                        const int* __restrict__ fi,
                                                        u16* __restrict__ Xg,
                                                        float* __restrict__ npts,
                                                        int Np, int S) {
  int q = blockIdx.x;
  int b = q / S;
  int t = threadIdx.x;
  int r = fi[q];
  const u32x4* src = (const u32x4*)(Xsrc + ((size_t)b * Np + r) * KP);
  u32x4* dst = (u32x4*)(Xg + (size_t)q * KP);
  dst[t] = src[t];
  int t2 = t + 128;
  if (t2 < 132) dst[t2] = src[t2];
  if (t == 0) {
    npts[(size_t)q * 2] = pts[((size_t)b * Np + r) * 2];
    npts[(size_t)q * 2 + 1] = pts[((size_t)b * Np + r) * 2 + 1];
  }
}

// ---------------- weight prep ----------------------------------------------
__global__ __launch_bounds__(256) void wd_transpose_kernel(const float* __restrict__ Wd,
                                                           u16* __restrict__ WdT) {
  __shared__ float tbuf[32][33];
  int tx = threadIdx.x & 31, ty = threadIdx.x >> 5;
  int ot = blockIdx.x * 32, dt = blockIdx.y * 32;
  #pragma unroll
  for (int j = 0; j < 4; ++j) {
    int o = ot + ty + 8 * j, d = dt + tx;
    tbuf[ty + 8 * j][tx] = (o < 1026 && d < 1026) ? Wd[(size_t)o * 1026 + d] : 0.f;
  }
  __syncthreads();
  #pragma unroll
  for (int j = 0; j < 4; ++j) {
    int d = dt + ty + 8 * j, o = ot + tx;
    if (o < KP) WdT[(size_t)d * KP + o] = f2bf(tbuf[tx][ty + 8 * j]);
  }
}

__global__ __launch_bounds__(256) void wagg_convert_kernel(const float* __restrict__ Wagg,
                                                           u16* __restrict__ Wa1,
                                                           u16* __restrict__ Wa2) {
  int c = blockIdx.x, t = threadIdx.x;
  const float* row = Wagg + (size_t)c * 2052;
  for (int d = t; d < KP; d += 256) {
    Wa1[(size_t)c * KP + d] = (d < 1026) ? f2bf(row[d]) : (u16)0;
    Wa2[(size_t)c * KP + d] = (d < 1026) ? f2bf(row[1026 + d]) : (u16)0;
  }
}

__global__ __launch_bounds__(256) void czero_kernel(const float* __restrict__ bdiff,
                                                    const float* __restrict__ Wagg,
                                                    const float* __restrict__ bagg,
                                                    float* __restrict__ czero) {
  int lane = threadIdx.x & 63, wv = threadIdx.x >> 6;
  int c = blockIdx.x * 4 + wv;
  float acc = 0.f;
  for (int o = lane; o < 1026; o += 64) acc += bdiff[o] * Wagg[(size_t)c * 2052 + o];
  #pragma unroll
  for (int off = 32; off; off >>= 1) acc += __shfl_xor(acc, off);
  if (lane == 0) czero[c] = acc + bagg[c];
}

// ---------------- bf16 MFMA GEMM: C[M,N] = A[M,K] @ Bt[N,K]^T ---------------
template <int BF16OUT>
__global__ __launch_bounds__(256) void gemm_bt_kernel(const u16* __restrict__ A,
                                                      const u16* __restrict__ Bt,
                                                      void* __restrict__ Cout,
                                                      int M, int N, int K, int ldc, int nvalid) {
  __shared__ __align__(16) u16 As[128 * 32];
  __shared__ __align__(16) u16 Bs[128 * 32];
  const int tid = threadIdx.x;
  const int lane = tid & 63;
  const int wv = tid >> 6;
  const int m0 = blockIdx.y * 128;
  const int n0 = blockIdx.x * 128;
  const int wm = (wv >> 1) * 64;
  const int wn = (wv & 1) * 64;

  f32x4 acc[4][4];
  #pragma unroll
  for (int i = 0; i < 4; ++i)
    #pragma unroll
    for (int j = 0; j < 4; ++j)
      #pragma unroll
      for (int c = 0; c < 4; ++c) acc[i][j][c] = 0.f;

  const int ch0 = wv * 2;
  const int rin = lane >> 2;
  const int cin = (lane & 3) * 8;

  for (int k0 = 0; k0 < K; k0 += 32) {
    #pragma unroll
    for (int i = 0; i < 2; ++i) {
      const int ch = ch0 + i;
      const int row = ch * 16 + rin;
      const u16* ga = A + (size_t)(m0 + row) * K + (k0 + cin);
      const u16* gb = Bt + (size_t)(n0 + row) * K + (k0 + cin);
      __builtin_amdgcn_global_load_lds((gvp)ga, (svp)(As + ch * 512), 16, 0, 0);
      __builtin_amdgcn_global_load_lds((gvp)gb, (svp)(Bs + ch * 512), 16, 0, 0);
    }
    __syncthreads();
    const int rf = lane & 15;
    const int qf = (lane >> 4) * 8;
    bf16x8 af[4], bfv[4];
    #pragma unroll
    for (int mi = 0; mi < 4; ++mi)
      af[mi] = *(const bf16x8*)(As + (wm + mi * 16 + rf) * 32 + qf);
    #pragma unroll
    for (int ni = 0; ni < 4; ++ni)
      bfv[ni] = *(const bf16x8*)(Bs + (wn + ni * 16 + rf) * 32 + qf);
    #pragma unroll
    for (int mi = 0; mi < 4; ++mi)
      #pragma unroll
      for (int ni = 0; ni < 4; ++ni)
        acc[mi][ni] = __builtin_amdgcn_mfma_f32_16x16x32_bf16(af[mi], bfv[ni], acc[mi][ni], 0, 0, 0);
    __syncthreads();
  }

  const int rq = (lane >> 4) * 4;
  const int cf = lane & 15;
  #pragma unroll
  for (int mi = 0; mi < 4; ++mi) {
    #pragma unroll
    for (int ni = 0; ni < 4; ++ni) {
      const int col = n0 + wn + ni * 16 + cf;
      #pragma unroll
      for (int r = 0; r < 4; ++r) {
        const int row = m0 + wm + mi * 16 + rq + r;
        const float v = acc[mi][ni][r];
        if (BF16OUT) {
          if (col < nvalid) ((u16*)Cout)[(size_t)row * ldc + col] = f2bf(v);
        } else {
          ((float*)Cout)[(size_t)row * ldc + col] = v;
        }
      }
    }
  }
}

// ---------------- fused gather + relu + LN + mean_k -------------------------
// MODE 0: bf16 X-row output (KP stride, pts tail)   MODE 1: bf16 flat 1024
template <int MODE>
__global__ __launch_bounds__(256) void h_epilogue_kernel(const float* __restrict__ Z1,
                                                         const float* __restrict__ Z2g,
                                                         const float* __restrict__ czero,
                                                         const int* __restrict__ idxK,
                                                         const int* __restrict__ fi,
                                                         const float* __restrict__ g,
                                                         const float* __restrict__ bb,
                                                         const float* __restrict__ npts,
                                                         void* __restrict__ outp,
                                                         int Np, int S) {
  __shared__ float r1[4];
  __shared__ float r2[4];
  int q = blockIdx.x;
  int b = q / S;
  int t = threadIdx.x;
  int lane = t & 63, wv = t >> 6;
  int fiv = fi[q];
  const f32x4* z2 = (const f32x4*)(Z2g + (size_t)q * 1024);
  const f32x4* zf = (const f32x4*)(Z1 + ((size_t)b * Np + fiv) * 1024);
  const f32x4* cz = (const f32x4*)czero;
  f32x4 base = z2[t] + cz[t] - zf[t];
  f32x4 gv = ((const f32x4*)g)[t];
  f32x4 bv = ((const f32x4*)bb)[t];
  f32x4 acc;
  #pragma unroll
  for (int c = 0; c < 4; ++c) acc[c] = 0.f;
  for (int k = 0; k < 24; ++k) {
    int n = idxK[(size_t)q * 24 + k];
    const f32x4* zr = (const f32x4*)(Z1 + ((size_t)b * Np + n) * 1024);
    f32x4 v = zr[t] + base;
    #pragma unroll
    for (int c = 0; c < 4; ++c) v[c] = fmaxf(v[c], 0.f);
    float s1 = v[0] + v[1] + v[2] + v[3];
    float s2 = v[0] * v[0] + v[1] * v[1] + v[2] * v[2] + v[3] * v[3];
    #pragma unroll
    for (int off = 32; off; off >>= 1) {
      s1 += __shfl_xor(s1, off);
      s2 += __shfl_xor(s2, off);
    }
    if (lane == 0) { r1[wv] = s1; r2[wv] = s2; }
    __syncthreads();
    s1 = r1[0] + r1[1] + r1[2] + r1[3];
    s2 = r2[0] + r2[1] + r2[2] + r2[3];
    __syncthreads();
    float m = s1 * (1.f / 1024.f);
    float var = s2 * (1.f / 1024.f) - m * m;
    float rs = rsqrtf(var + 1e-5f);
    #pragma unroll
    for (int c = 0; c < 4; ++c) acc[c] += (v[c] - m) * rs * gv[c] + bv[c];
  }
  #pragma unroll
  for (int c = 0; c < 4; ++c) acc[c] *= (1.f / 24.f);
  u16x4 o4;
  #pragma unroll
  for (int c = 0; c < 4; ++c) o4[c] = f2bf(acc[c]);
  if (MODE == 0) {
    u16* X = (u16*)outp;
    size_t ro = (size_t)q * KP;
    *(u16x4*)(X + ro + t * 4) = o4;
    if (t == 0) {
      X[ro + 1024] = f2bf(npts[(size_t)q * 2]);
      X[ro + 1025] = f2bf(npts[(size_t)q * 2 + 1]);
    }
    if (t < 15) ((u32*)(X + ro + 1026))[t] = 0;
  } else {
    *(u16x4*)((u16*)outp + (size_t)q * 1024 + t * 4) = o4;
  }
}

// ---------------- MLP MFMA GEMM: P[blk] = W_tile(fp32->bf16) @ Fb^T ---------
// W fp32 [M,K]; Fb bf16 [32,K]; grid = (M/128) << KSBITS blocks.
// A staged via global_load_lds (XOR-swizzled 16B groups, conflict-free);
// converted to bf16 fragments in-register. Partials P[blk][128][32] fp32.
template <int KSBITS, int NST>
__global__ __launch_bounds__(256, 4) void mlp_mfma_kernel(const float* __restrict__ W,
                                                          const u16* __restrict__ Fb,
                                                          float* __restrict__ P, int K) {
  __shared__ __align__(16) float Asf[128 * 32];
  __shared__ __align__(16) u16 Fsb[32 * 40];
  const int tid = threadIdx.x, lane = tid & 63, wv = tid >> 6;
  const int ot = blockIdx.x >> KSBITS;
  const int ks = blockIdx.x & ((1 << KSBITS) - 1);
  const int m0 = ot * 128;
  const int k0b = ks * (NST * 32);
  const int arow = lane >> 3;
  const int agrp = lane & 7;
  const int rf = lane & 15, quad = lane >> 4;

  f32x4 acc[2][2];
  #pragma unroll
  for (int i = 0; i < 2; ++i)
    #pragma unroll
    for (int j = 0; j < 2; ++j)
      #pragma unroll
      for (int c = 0; c < 4; ++c) acc[i][j][c] = 0.f;

  for (int st = 0; st < NST; ++st) {
    const int k0 = k0b + st * 32;
    #pragma unroll
    for (int i = 0; i < 4; ++i) {
      const int row = wv * 32 + i * 8 + arow;
      const int g = agrp ^ (row & 7);
      const float* ga = W + (size_t)(m0 + row) * K + k0 + g * 4;
      __builtin_amdgcn_global_load_lds((gvp)ga, (svp)(Asf + (wv * 32 + i * 8) * 32), 16, 0, 0);
    }
    if (tid < 128) {
      const int fr = tid >> 2, fc = (tid & 3) * 8;
      u32x4 tmp = *(const u32x4*)(Fb + (size_t)fr * K + k0 + fc);
      *(u32x4*)(Fsb + fr * 40 + fc) = tmp;
    }
    __syncthreads();
    bf16x8 bfr[2];
    #pragma unroll
    for (int ni = 0; ni < 2; ++ni)
      bfr[ni] = *(const bf16x8*)(Fsb + (ni * 16 + rf) * 40 + quad * 8);
    #pragma unroll
    for (int mi = 0; mi < 2; ++mi) {
      const float* ap = Asf + (size_t)(wv * 32 + mi * 16 + rf) * 32;
      f32x4 a0 = *(const f32x4*)(ap + (((quad * 2) ^ (rf & 7)) * 4));
      f32x4 a1 = *(const f32x4*)(ap + (((quad * 2 + 1) ^ (rf & 7)) * 4));
      union { bf16x8 v; u16 h[8]; } af;
      #pragma unroll
      for (int c = 0; c < 4; ++c) { af.h[c] = f2bf(a0[c]); af.h[4 + c] = f2bf(a1[c]); }
      #pragma unroll
      for (int ni = 0; ni < 2; ++ni)
        acc[mi][ni] = __builtin_amdgcn_mfma_f32_16x16x32_bf16(af.v, bfr[ni], acc[mi][ni], 0, 0, 0);
    }
    __syncthreads();
  }

  float* Pb = P + (size_t)blockIdx.x * 4096;
  const int rq = (lane >> 4) * 4, cf = lane & 15;
  #pragma unroll
  for (int mi = 0; mi < 2; ++mi)
    #pragma unroll
    for (int ni = 0; ni < 2; ++ni)
      #pragma unroll
      for (int r = 0; r < 4; ++r)
        Pb[(wv * 32 + mi * 16 + rq + r) * 32 + ni * 16 + cf] = acc[mi][ni][r];
}

// ---------------- K-split partial reductions (bias fused) -------------------
__global__ __launch_bounds__(256) void reduce_flat_kernel(const float* __restrict__ P,
                                                          const float* __restrict__ bias,
                                                          u16* __restrict__ x1bf) {
  int idx = blockIdx.x * 256 + threadIdx.x;  // 32768
  int o = idx >> 5, b = idx & 31;
  float s = bias[o];
  const float* p = P + ((size_t)(o >> 7) * 64) * 4096 + (o & 127) * 32 + b;
  #pragma unroll 8
  for (int ks = 0; ks < 64; ++ks) s += p[(size_t)ks * 4096];
  x1bf[(size_t)b * 1024 + o] = f2bf(s);
}

__global__ __launch_bounds__(256) void reduce_dim_kernel(const float* __restrict__ P,
                                                         const float* __restrict__ bias,
                                                         float* __restrict__ out) {
  int idx = blockIdx.x * 256 + threadIdx.x;  // 131072
  int o = idx >> 5, b = idx & 31;
  float s = bias[o];
  const float* p = P + ((size_t)(o >> 7) * 8) * 4096 + (o & 127) * 32 + b;
  #pragma unroll
  for (int ks = 0; ks < 8; ++ks) s += p[(size_t)ks * 4096];
  out[(size_t)b * 4096 + o] = s;
}

// ---------------------------------------------------------------------------
extern "C" void kernel_launch(void* const* d_in, const int* in_sizes, int n_in,
                              void* d_out, int out_size, void* d_ws, size_t ws_size,
                              hipStream_t stream) {
  const float* fmap  = (const float*)d_in[0];
  const float* pts   = (const float*)d_in[1];
  const float* Wdiff = (const float*)d_in[2];
  const float* bdiff = (const float*)d_in[3];
  const float* Wagg  = (const float*)d_in[4];
  const float* bagg  = (const float*)d_in[5];
  const float* lng   = (const float*)d_in[6];
  const float* lnb   = (const float*)d_in[7];
  const float* Wflat = (const float*)d_in[8];
  const float* bflat = (const float*)d_in[9];
  const float* Wdim  = (const float*)d_in[10];
  const float* bdim  = (const float*)d_in[11];
  float* out = (float*)d_out;

  char* w = (char*)d_ws;
  size_t off = 0;
  auto alloc = [&](size_t n) { char* p = w + off; off += (n + 255) & ~(size_t)255; return p; };

  float* Z1    = (float*)alloc(16384ull * 1024 * 4);  // 67.1 MB
  float* Z2g   = (float*)alloc(4096ull * 1024 * 4);   // 16.8 MB
  u16* Xbf0  = (u16*)alloc(16384ull * KP * 2);
  u16* X1bf  = (u16*)alloc(4096ull * KP * 2);
  u16* Xg    = (u16*)alloc(4096ull * KP * 2);
  u16* WdT   = (u16*)alloc((size_t)NP0 * KP * 2);
  u16* Wa1   = (u16*)alloc(1024ull * KP * 2);
  u16* Wa2   = (u16*)alloc(1024ull * KP * 2);
  u16* Wcomb = (u16*)alloc(1024ull * KP * 2);
  float* czero = (float*)alloc(1024 * 4);
  int* fi0   = (int*)alloc(32 * 128 * 4);
  int* fi1   = (int*)alloc(32 * 32 * 4);
  int* idx0  = (int*)alloc(32 * 128 * 24 * 4);
  int* idx1  = (int*)alloc(32 * 32 * 24 * 4);
  float* npts0 = (float*)alloc(32 * 128 * 2 * 4);
  float* npts1 = (float*)alloc(32 * 32 * 2 * 4);
  u16* fea2bf = (u16*)alloc(32ull * 32768 * 2);       // 2 MB bf16
  u16* x1bf   = (u16*)alloc(32ull * 1024 * 2);        // 64 KB bf16
  float* Pf   = (float*)alloc(512ull * 4096 * 4);     // 8 MB partials (flat)
  float* Pd   = (float*)alloc(256ull * 4096 * 4);     // 4 MB partials (dim)

  // ---- stage-0 inputs
  bilinear_fused_kernel<<<dim3(32, 32), 256, 0, stream>>>(fmap, pts, Xbf0);

  // ---- stage 0 (Np=512, S=128)
  fps_kernel<8><<<32, 64, 0, stream>>>(pts, fi0, 512, 128);
  gather_fi_kernel<<<4096, 128, 0, stream>>>(Xbf0, pts, fi0, Xg, npts0, 512, 128);
  knn_kernel<8><<<1024, 256, 0, stream>>>(npts0, pts, idx0, 512, 128);
  wd_transpose_kernel<<<dim3(33, 36), 256, 0, stream>>>(Wdiff, WdT);
  wagg_convert_kernel<<<1024, 256, 0, stream>>>(Wagg, Wa1, Wa2);
  czero_kernel<<<256, 256, 0, stream>>>(bdiff, Wagg, bagg, czero);
  gemm_bt_kernel<1><<<dim3(9, 8), 256, 0, stream>>>(Wa1, WdT, Wcomb, 1024, NP0, KP, KP, KP);
  gemm_bt_kernel<0><<<dim3(8, 128), 256, 0, stream>>>(Xbf0, Wcomb, Z1, 16384, 1024, KP, 1024, 1024);
  gemm_bt_kernel<0><<<dim3(8, 32), 256, 0, stream>>>(Xg, Wa2, Z2g, 4096, 1024, KP, 1024, 1024);
  h_epilogue_kernel<0><<<4096, 256, 0, stream>>>(Z1, Z2g, czero, idx0, fi0, lng, lnb, npts0,
                                                 X1bf, 512, 128);

  // ---- stage 1 (Np=128, S=32)
  fps_kernel<2><<<32, 64, 0, stream>>>(npts0, fi1, 128, 32);
  gather_fi_kernel<<<1024, 128, 0, stream>>>(X1bf, npts0, fi1, Xg, npts1, 128, 32);
  knn_kernel<2><<<256, 256, 0, stream>>>(npts1, npts0, idx1, 128, 32);
  wd_transpose_kernel<<<dim3(33, 36), 256, 0, stream>>>(Wdiff + 1026 * 1026, WdT);
  wagg_convert_kernel<<<1024, 256, 0, stream>>>(Wagg + 1024 * 2052, Wa1, Wa2);
  czero_kernel<<<256, 256, 0, stream>>>(bdiff + 1026, Wagg + 1024 * 2052, bagg + 1024, czero);
  gemm_bt_kernel<1><<<dim3(9, 8), 256, 0, stream>>>(Wa1, WdT, Wcomb, 1024, NP0, KP, KP, KP);
  gemm_bt_kernel<0><<<dim3(8, 32), 256, 0, stream>>>(X1bf, Wcomb, Z1, 4096, 1024, KP, 1024, 1024);
  gemm_bt_kernel<0><<<dim3(8, 8), 256, 0, stream>>>(Xg, Wa2, Z2g, 1024, 1024, KP, 1024, 1024);
  h_epilogue_kernel<1><<<1024, 256, 0, stream>>>(Z1, Z2g, czero, idx1, fi1, lng + 1024, lnb + 1024,
                                                 npts1, fea2bf, 128, 32);

  // ---- final MLP (MFMA, K-split partials + reduce)
  mlp_mfma_kernel<6, 16><<<512, 256, 0, stream>>>(Wflat, fea2bf, Pf, 32768);
  reduce_flat_kernel<<<128, 256, 0, stream>>>(Pf, bflat, x1bf);
  mlp_mfma_kernel<3, 4><<<256, 256, 0, stream>>>(Wdim, x1bf, Pd, 1024);
  reduce_dim_kernel<<<512, 256, 0, stream>>>(Pd, bdim, out);
}